// Round 4
// baseline (1057.543 us; speedup 1.0000x reference)
//
#include <hip/hip_runtime.h>
#include <hip/hip_bf16.h>

typedef unsigned short ushort;
typedef unsigned int uint;
typedef __attribute__((ext_vector_type(8))) short short8;
typedef __attribute__((ext_vector_type(4))) float floatx4;

#define NEG_SLOPE 0.2f

__device__ __forceinline__ float bu2f(ushort u) {
  uint t = ((uint)u) << 16;
  return __uint_as_float(t);
}
__device__ __forceinline__ ushort f2bu(float f) {
  __hip_bfloat16 h = __float2bfloat16(f);
  return *(ushort*)&h;
}
__device__ __forceinline__ float lo2f(uint u) { return __uint_as_float(u << 16); }
__device__ __forceinline__ float hi2f(uint u) { return __uint_as_float(u & 0xffff0000u); }
__device__ __forceinline__ float lrelu(float e) { return (e > 0.f) ? e : NEG_SLOPE * e; }

// ---------------- CSR build ----------------
__global__ void zero_int_kernel(int* __restrict__ p, int n) {
  int i = blockIdx.x * blockDim.x + threadIdx.x;
  if (i < n) p[i] = 0;
}

__global__ void hist_kernel(const int* __restrict__ dst, int* __restrict__ deg, int E) {
  int e = blockIdx.x * blockDim.x + threadIdx.x;
  if (e < E) atomicAdd(&deg[dst[e]], 1);
}

__global__ void scan1_kernel(const int* __restrict__ deg, int* __restrict__ part,
                             int* __restrict__ bsums, int n) {
  __shared__ int sdata[256];
  int t = threadIdx.x;
  int base = blockIdx.x * 1024;
  int v[4]; int s = 0;
#pragma unroll
  for (int j = 0; j < 4; ++j) {
    int idx = base + t * 4 + j;
    v[j] = (idx < n) ? deg[idx] : 0;
    s += v[j];
  }
  sdata[t] = s;
  __syncthreads();
  for (int off = 1; off < 256; off <<= 1) {
    int x = 0;
    if (t >= off) x = sdata[t - off];
    __syncthreads();
    if (t >= off) sdata[t] += x;
    __syncthreads();
  }
  if (t == 255) bsums[blockIdx.x] = sdata[255];
  int run = (t > 0) ? sdata[t - 1] : 0;
#pragma unroll
  for (int j = 0; j < 4; ++j) {
    int idx = base + t * 4 + j;
    if (idx < n) part[idx] = run;
    run += v[j];
  }
}

__global__ void scan2_kernel(int* __restrict__ bsums, int nb) {
  __shared__ int sdata[256];
  int t = threadIdx.x;
  sdata[t] = (t < nb) ? bsums[t] : 0;
  __syncthreads();
  for (int off = 1; off < 256; off <<= 1) {
    int x = 0;
    if (t >= off) x = sdata[t - off];
    __syncthreads();
    if (t >= off) sdata[t] += x;
    __syncthreads();
  }
  if (t < nb) bsums[t] = (t > 0) ? sdata[t - 1] : 0;
}

__global__ void scan3_kernel(const int* __restrict__ part, const int* __restrict__ bsums,
                             int* __restrict__ rowptr, int* __restrict__ cursor,
                             int n, int Etot) {
  int i = blockIdx.x * blockDim.x + threadIdx.x;
  if (i < n) {
    int v = part[i] + bsums[i >> 10];
    rowptr[i] = v;
    cursor[i] = v;
  }
  if (i == 0) rowptr[n] = Etot;
}

__global__ void scatter_kernel(const int* __restrict__ src, const int* __restrict__ dst,
                               int* __restrict__ cursor, int* __restrict__ csr_src, int E) {
  int e = blockIdx.x * blockDim.x + threadIdx.x;
  if (e < E) {
    int pos = atomicAdd(&cursor[dst[e]], 1);
    csr_src[pos] = src[e];
  }
}

// ---------------- splits ----------------
__global__ void splitx_kernel(const float* __restrict__ x, ushort* __restrict__ xhi,
                              ushort* __restrict__ xlo, int n) {
  int base = (blockIdx.x * blockDim.x + threadIdx.x) * 4;
  if (base >= n) return;
  float4 a = *(const float4*)(x + base);
  float v[4] = {a.x, a.y, a.z, a.w};
  ushort hi[4], lo[4];
#pragma unroll
  for (int j = 0; j < 4; ++j) {
    hi[j] = f2bu(v[j]);
    lo[j] = f2bu(v[j] - bu2f(hi[j]));
  }
  uint2 ho, loo;
  ho.x = (uint)hi[0] | ((uint)hi[1] << 16);
  ho.y = (uint)hi[2] | ((uint)hi[3] << 16);
  loo.x = (uint)lo[0] | ((uint)lo[1] << 16);
  loo.y = (uint)lo[2] | ((uint)lo[3] << 16);
  *(uint2*)(xhi + base) = ho;
  *(uint2*)(xlo + base) = loo;
}

__global__ void splitW_kernel(const float* __restrict__ W, ushort* __restrict__ WtH,
                              ushort* __restrict__ WtL, int K, int Nc) {
  int idx = blockIdx.x * blockDim.x + threadIdx.x;
  if (idx >= K * Nc) return;
  int n = idx / K, k = idx - n * K;
  float w = W[(size_t)k * Nc + n];
  ushort hi = f2bu(w);
  WtH[idx] = hi;
  WtL[idx] = f2bu(w - bu2f(hi));
}

// ---------------- split-bf16 MFMA GEMM ----------------
#define GBM 128
#define GBN 64
#define GBK 32
#define SA 40

__global__ __launch_bounds__(256) void gemm_split_kernel(
    const ushort* __restrict__ Ah, const ushort* __restrict__ Al,
    const ushort* __restrict__ Bh, const ushort* __restrict__ Bl,
    ushort* __restrict__ C, int M, int K, int Nc) {
  __shared__ ushort AsH[GBM * SA];
  __shared__ ushort AsL[GBM * SA];
  __shared__ ushort BsH[GBN * SA];
  __shared__ ushort BsL[GBN * SA];
  int tid = threadIdx.x;
  int lane = tid & 63;
  int wave = tid >> 6;
  int wm = wave & 1, wn = wave >> 1;
  int rowBase = blockIdx.y * GBM;
  int colBase = blockIdx.x * GBN;
  int q = lane >> 4;
  int ln = lane & 15;

  floatx4 acc[4][2] = {};

  for (int k0 = 0; k0 < K; k0 += GBK) {
#pragma unroll
    for (int it = 0; it < 2; ++it) {
      int i = tid + it * 256;
      int r = i >> 2, seg = i & 3;
      int grow = rowBase + r;
      uint4 vh = {0u, 0u, 0u, 0u}, vl = {0u, 0u, 0u, 0u};
      if (grow < M) {
        size_t off = (size_t)grow * K + k0 + seg * 8;
        vh = *(const uint4*)(Ah + off);
        vl = *(const uint4*)(Al + off);
      }
      *(uint4*)&AsH[r * SA + seg * 8] = vh;
      *(uint4*)&AsL[r * SA + seg * 8] = vl;
    }
    {
      int n = tid >> 2, seg = tid & 3;
      int gcol = colBase + n;
      uint4 vh = {0u, 0u, 0u, 0u}, vl = {0u, 0u, 0u, 0u};
      if (gcol < Nc) {
        size_t off = (size_t)gcol * K + k0 + seg * 8;
        vh = *(const uint4*)(Bh + off);
        vl = *(const uint4*)(Bl + off);
      }
      *(uint4*)&BsH[n * SA + seg * 8] = vh;
      *(uint4*)&BsL[n * SA + seg * 8] = vl;
    }
    __syncthreads();
    short8 afH[4], afL[4], bfH[2], bfL[2];
#pragma unroll
    for (int mt = 0; mt < 4; ++mt) {
      int r = (wm * 64 + mt * 16 + ln) * SA + q * 8;
      afH[mt] = *(const short8*)&AsH[r];
      afL[mt] = *(const short8*)&AsL[r];
    }
#pragma unroll
    for (int nt = 0; nt < 2; ++nt) {
      int r = (wn * 32 + nt * 16 + ln) * SA + q * 8;
      bfH[nt] = *(const short8*)&BsH[r];
      bfL[nt] = *(const short8*)&BsL[r];
    }
#pragma unroll
    for (int mt = 0; mt < 4; ++mt)
#pragma unroll
      for (int nt = 0; nt < 2; ++nt) {
        acc[mt][nt] = __builtin_amdgcn_mfma_f32_16x16x32_bf16(afH[mt], bfH[nt], acc[mt][nt], 0, 0, 0);
        acc[mt][nt] = __builtin_amdgcn_mfma_f32_16x16x32_bf16(afH[mt], bfL[nt], acc[mt][nt], 0, 0, 0);
        acc[mt][nt] = __builtin_amdgcn_mfma_f32_16x16x32_bf16(afL[mt], bfH[nt], acc[mt][nt], 0, 0, 0);
      }
    __syncthreads();
  }
#pragma unroll
  for (int mt = 0; mt < 4; ++mt) {
#pragma unroll
    for (int nt = 0; nt < 2; ++nt) {
      int col = colBase + wn * 32 + nt * 16 + ln;
      if (col < Nc) {
#pragma unroll
        for (int r = 0; r < 4; ++r) {
          int row = rowBase + wm * 64 + mt * 16 + q * 4 + r;
          if (row < M) C[(size_t)row * Nc + col] = f2bu(acc[mt][nt][r]);
        }
      }
    }
  }
}

// ---------------- el/er layer 1/2 (Dh=32, F=128): vectorized uint4 loads ----------------
__global__ void elr128_kernel(const ushort* __restrict__ feat, const float* __restrict__ al,
                              const float* __restrict__ ar, float* __restrict__ el,
                              float* __restrict__ er, int N) {
  int g = blockIdx.x * blockDim.x + threadIdx.x;
  if (g >= N * 4) return;
  int n = g >> 2, h = g & 3;
  const uint4* fp = (const uint4*)(feat + (size_t)n * 128 + h * 32);
  const float* alp = al + h * 32;
  const float* arp = ar + h * 32;
  float sl = 0.f, sr = 0.f;
#pragma unroll
  for (int b = 0; b < 4; ++b) {
    uint4 u = fp[b];
    uint w[4] = {u.x, u.y, u.z, u.w};
#pragma unroll
    for (int j = 0; j < 4; ++j) {
      int d = b * 8 + j * 2;
      float f0 = lo2f(w[j]), f1 = hi2f(w[j]);
      sl += f0 * alp[d] + f1 * alp[d + 1];
      sr += f0 * arp[d] + f1 * arp[d + 1];
    }
  }
  el[g] = sl;
  er[g] = sr;
}

// ---------------- el/er layer 3 (Dh=47, F=188): scalar ----------------
__global__ void elr3_kernel(const ushort* __restrict__ feat, const float* __restrict__ al,
                            const float* __restrict__ ar, float* __restrict__ el,
                            float* __restrict__ er, int N) {
  int g = blockIdx.x * blockDim.x + threadIdx.x;
  if (g >= N * 4) return;
  int n = g >> 2, h = g & 3;
  const ushort* fp = feat + (size_t)n * 188 + h * 47;
  float sl = 0.f, sr = 0.f;
  for (int d = 0; d < 47; ++d) {
    float f = bu2f(fp[d]);
    sl += f * al[h * 47 + d];
    sr += f * ar[h * 47 + d];
  }
  el[g] = sl;
  er[g] = sr;
}

// ---------------- edge attention weights (transposed) + per-node denominator ----------
// Round-1-verified structure; only the wbuf store index changed to transposed
// layout wT[h][E] so agg lanes read their head's weight stream directly.
__global__ __launch_bounds__(256) void edgew_kernel(
    const int* __restrict__ rowptr, const int* __restrict__ csr_src,
    const float* __restrict__ el, const float* __restrict__ er,
    float* __restrict__ wbufT, float* __restrict__ den, int N, int Estride) {
  int lane = threadIdx.x & 63;
  int v = blockIdx.x * 4 + (threadIdx.x >> 6);
  if (v >= N) return;
  int hh = lane & 3;
  float eh = er[(size_t)v * 4 + hh];
  int r0 = rowptr[v], r1 = rowptr[v + 1];
  float dsum = 0.f;
  for (int i0 = r0; i0 < r1; i0 += 16) {
    int i = i0 + (lane >> 2);
    if (i < r1) {
      int sv = csr_src[i];
      float w = __expf(lrelu(el[(size_t)sv * 4 + hh] + eh));
      wbufT[(size_t)hh * Estride + i] = w;
      dsum += w;
    }
  }
#pragma unroll
  for (int off = 4; off < 64; off <<= 1) dsum += __shfl_xor(dsum, off);
  if (lane < 4) den[(size_t)v * 4 + hh] = dsum;
}

// ---------------- lean layer 1/2 aggregation: readlane src + streamed weights -------
__global__ __launch_bounds__(256) void agg128_kernel(
    const int* __restrict__ rowptr, const int* __restrict__ csr_src,
    const ushort* __restrict__ feat, const float* __restrict__ wbufT,
    const float* __restrict__ den, const float* __restrict__ bias,
    ushort* __restrict__ hhi, ushort* __restrict__ hlo, int N, int Estride) {
  int lane = threadIdx.x & 63;
  int v = blockIdx.x * 4 + (threadIdx.x >> 6);
  if (v >= N) return;
  int r0 = rowptr[v], r1 = rowptr[v + 1];
  int hf = lane >> 4;  // head owning features 2*lane, 2*lane+1
  const uint* fb = (const uint*)feat;
  const float* wp = wbufT + (size_t)hf * Estride;  // per-lane-constant base
  float a0 = 0.f, a1 = 0.f;
  for (int i0 = r0; i0 < r1; i0 += 64) {
    int i = i0 + lane;
    int sv = (i < r1) ? csr_src[i] : 0;
    int cnt = r1 - i0;
    if (cnt > 64) cnt = 64;
#pragma unroll 4
    for (int j = 0; j < cnt; ++j) {
      int s = __builtin_amdgcn_readlane(sv, j);
      float x = wp[i0 + j];
      uint u = fb[((size_t)(uint)s << 6) + lane];
      a0 = fmaf(x, lo2f(u), a0);
      a1 = fmaf(x, hi2f(u), a1);
    }
  }
  float d = den[(size_t)v * 4 + hf];
  float o0 = (d > 0.f) ? a0 / d : 0.f;
  float o1 = (d > 0.f) ? a1 / d : 0.f;
  o0 = fmaxf(o0 + bias[2 * lane], 0.f);
  o1 = fmaxf(o1 + bias[2 * lane + 1], 0.f);
  ushort h0 = f2bu(o0), h1 = f2bu(o1);
  ushort l0 = f2bu(o0 - bu2f(h0)), l1 = f2bu(o1 - bu2f(h1));
  ((uint*)hhi)[(size_t)v * 64 + lane] = (uint)h0 | ((uint)h1 << 16);
  ((uint*)hlo)[(size_t)v * 64 + lane] = (uint)l0 | ((uint)l1 << 16);
}

// ---------------- lean layer 3 aggregation + bias + head-mean + log_softmax ---------
__global__ __launch_bounds__(256) void agg3_kernel(
    const int* __restrict__ rowptr, const int* __restrict__ csr_src,
    const ushort* __restrict__ feat, const float* __restrict__ wbufT,
    const float* __restrict__ den, const float* __restrict__ bias,
    float* __restrict__ out, int N, int Estride) {
  __shared__ float svm[4][188];
  int lane = threadIdx.x & 63;
  int w = threadIdx.x >> 6;
  int v = blockIdx.x * 4 + w;
  bool valid = (v < N);
  int r0 = 0, r1 = 0;
  if (valid) {
    r0 = rowptr[v];
    r1 = rowptr[v + 1];
  }
  // lane owns features 2l,2l+1 and (lanes<30) 128+2l,129+2l
  int fa = 2 * lane, fbi = 2 * lane + 1;
  int fc = 128 + 2 * lane, fd = 129 + 2 * lane;
  bool hasC = (fd < 188);
  int ha = fa / 47, hb = fbi / 47;
  int hc = hasC ? fc / 47 : 3, hd = hasC ? fd / 47 : 3;
  const uint* fpb = (const uint*)feat;  // feat row: 94 uints
  const float* wap = wbufT + (size_t)ha * Estride;
  const float* wbp = wbufT + (size_t)hb * Estride;
  const float* wcp = wbufT + (size_t)hc * Estride;
  const float* wdp = wbufT + (size_t)hd * Estride;
  float aa = 0.f, ab = 0.f, ac = 0.f, ad = 0.f;
  for (int i0 = r0; i0 < r1; i0 += 64) {
    int i = i0 + lane;
    int sv = (i < r1) ? csr_src[i] : 0;
    int cnt = r1 - i0;
    if (cnt > 64) cnt = 64;
#pragma unroll 2
    for (int j = 0; j < cnt; ++j) {
      int s = __builtin_amdgcn_readlane(sv, j);
      float xa = wap[i0 + j];
      float xb = wbp[i0 + j];
      const uint* fr = fpb + (size_t)(uint)s * 94;
      uint u0 = fr[lane];
      aa = fmaf(xa, lo2f(u0), aa);
      ab = fmaf(xb, hi2f(u0), ab);
      if (hasC) {
        float xc = wcp[i0 + j];
        float xd = wdp[i0 + j];
        uint u1 = fr[64 + lane];
        ac = fmaf(xc, lo2f(u1), ac);
        ad = fmaf(xd, hi2f(u1), ad);
      }
    }
  }
  float da = 0.f, db = 0.f, dc = 1.f, dd = 1.f;
  if (valid) {
    const float* dp = den + (size_t)v * 4;
    da = dp[ha];
    db = dp[hb];
    if (hasC) {
      dc = dp[hc];
      dd = dp[hd];
    }
  }
  float oa = ((da > 0.f) ? aa / da : 0.f) + bias[fa];
  float ob = ((db > 0.f) ? ab / db : 0.f) + bias[fbi];
  if (valid) {
    svm[w][fa] = oa;
    svm[w][fbi] = ob;
    if (hasC) {
      float oc = ((dc > 0.f) ? ac / dc : 0.f) + bias[fc];
      float od = ((dd > 0.f) ? ad / dd : 0.f) + bias[fd];
      svm[w][fc] = oc;
      svm[w][fd] = od;
    }
  }
  __syncthreads();
  float val = -1e30f;
  if (valid && lane < 47)
    val = 0.25f * (svm[w][lane] + svm[w][47 + lane] + svm[w][94 + lane] + svm[w][141 + lane]);
  float mx = val;
#pragma unroll
  for (int off = 32; off > 0; off >>= 1) mx = fmaxf(mx, __shfl_xor(mx, off));
  float ex = (lane < 47) ? __expf(val - mx) : 0.f;
  float sum = ex;
#pragma unroll
  for (int off = 32; off > 0; off >>= 1) sum += __shfl_xor(sum, off);
  float res = val - mx - logf(sum);
  if (valid && lane < 47) out[(size_t)v * 47 + lane] = res;
}

// ---------------- host orchestration ----------------
extern "C" void kernel_launch(void* const* d_in, const int* in_sizes, int n_in,
                              void* d_out, int out_size, void* d_ws, size_t ws_size,
                              hipStream_t stream) {
  const int N = 100000, E = 1600000, IN = 256;
  const int F = 128;   // H*D
  const int F3 = 188;  // H*C

  const float* x = (const float*)d_in[0];
  const int* src = (const int*)d_in[1];
  const int* dst = (const int*)d_in[2];
  const float* W1 = (const float*)d_in[3];
  const float* al1 = (const float*)d_in[4];
  const float* ar1 = (const float*)d_in[5];
  const float* b1 = (const float*)d_in[6];
  const float* W2 = (const float*)d_in[7];
  const float* al2 = (const float*)d_in[8];
  const float* ar2 = (const float*)d_in[9];
  const float* b2 = (const float*)d_in[10];
  const float* W3 = (const float*)d_in[11];
  const float* al3 = (const float*)d_in[12];
  const float* ar3 = (const float*)d_in[13];
  const float* b3 = (const float*)d_in[14];

  char* p = (char*)d_ws;
  auto alloc = [&](size_t bytes) -> char* {
    char* r = p;
    p += (bytes + 255) & ~(size_t)255;
    return r;
  };
  ushort* xhi = (ushort*)alloc((size_t)N * IN * sizeof(ushort));
  ushort* xlo = (ushort*)alloc((size_t)N * IN * sizeof(ushort));
  ushort* feat = (ushort*)alloc((size_t)N * F3 * sizeof(ushort));
  ushort* Wt1h = (ushort*)alloc((size_t)F * IN * sizeof(ushort));
  ushort* Wt1l = (ushort*)alloc((size_t)F * IN * sizeof(ushort));
  ushort* Wt2h = (ushort*)alloc((size_t)F * F * sizeof(ushort));
  ushort* Wt2l = (ushort*)alloc((size_t)F * F * sizeof(ushort));
  ushort* Wt3h = (ushort*)alloc((size_t)F3 * F * sizeof(ushort));
  ushort* Wt3l = (ushort*)alloc((size_t)F3 * F * sizeof(ushort));
  float* el = (float*)alloc((size_t)N * 4 * sizeof(float));
  float* er = (float*)alloc((size_t)N * 4 * sizeof(float));
  int* deg = (int*)alloc((size_t)N * sizeof(int));
  int* part = (int*)alloc((size_t)N * sizeof(int));
  int* bsums = (int*)alloc(256 * sizeof(int));
  int* rowptr = (int*)alloc((size_t)(N + 1) * sizeof(int));
  int* cursor = (int*)alloc((size_t)N * sizeof(int));
  int* csr_src = (int*)alloc((size_t)E * sizeof(int));
  float* wbufT = (float*)alloc(((size_t)E * 4 + 16) * sizeof(float));
  float* den = (float*)alloc((size_t)N * 4 * sizeof(float));

  // h (layers 2/3 input) aliases the x split buffers — x is consumed by the
  // layer-1 GEMM before agg128 overwrites these (single-stream ordering).
  ushort* hhi = xhi;
  ushort* hlo = xlo;

  // ---- CSR build ----
  zero_int_kernel<<<(N + 255) / 256, 256, 0, stream>>>(deg, N);
  hist_kernel<<<(E + 255) / 256, 256, 0, stream>>>(dst, deg, E);
  int nb = (N + 1023) / 1024;
  scan1_kernel<<<nb, 256, 0, stream>>>(deg, part, bsums, N);
  scan2_kernel<<<1, 256, 0, stream>>>(bsums, nb);
  scan3_kernel<<<(N + 255) / 256, 256, 0, stream>>>(part, bsums, rowptr, cursor, N, E);
  scatter_kernel<<<(E + 255) / 256, 256, 0, stream>>>(src, dst, cursor, csr_src, E);

  // ---- splits ----
  splitx_kernel<<<(N * IN / 4 + 255) / 256, 256, 0, stream>>>(x, xhi, xlo, N * IN);
  splitW_kernel<<<(IN * F + 255) / 256, 256, 0, stream>>>(W1, Wt1h, Wt1l, IN, F);
  splitW_kernel<<<(F * F + 255) / 256, 256, 0, stream>>>(W2, Wt2h, Wt2l, F, F);
  splitW_kernel<<<(F * F3 + 255) / 256, 256, 0, stream>>>(W3, Wt3h, Wt3l, F, F3);

  int rowBlocks = (N + GBM - 1) / GBM;  // 782
  int nodeBlocks = (N + 3) / 4;

  // ---- layer 1: IN=256 -> 128 ----
  gemm_split_kernel<<<dim3(F / GBN, rowBlocks), 256, 0, stream>>>(
      xhi, xlo, Wt1h, Wt1l, feat, N, IN, F);
  elr128_kernel<<<(N * 4 + 255) / 256, 256, 0, stream>>>(feat, al1, ar1, el, er, N);
  edgew_kernel<<<nodeBlocks, 256, 0, stream>>>(rowptr, csr_src, el, er, wbufT, den, N, E);
  agg128_kernel<<<nodeBlocks, 256, 0, stream>>>(rowptr, csr_src, feat, wbufT, den, b1,
                                                hhi, hlo, N, E);

  // ---- layer 2: 128 -> 128 ----
  gemm_split_kernel<<<dim3(F / GBN, rowBlocks), 256, 0, stream>>>(
      hhi, hlo, Wt2h, Wt2l, feat, N, F, F);
  elr128_kernel<<<(N * 4 + 255) / 256, 256, 0, stream>>>(feat, al2, ar2, el, er, N);
  edgew_kernel<<<nodeBlocks, 256, 0, stream>>>(rowptr, csr_src, el, er, wbufT, den, N, E);
  agg128_kernel<<<nodeBlocks, 256, 0, stream>>>(rowptr, csr_src, feat, wbufT, den, b2,
                                                hhi, hlo, N, E);

  // ---- layer 3: 128 -> 188, fused epilogue ----
  gemm_split_kernel<<<dim3((F3 + GBN - 1) / GBN, rowBlocks), 256, 0, stream>>>(
      hhi, hlo, Wt3h, Wt3l, feat, N, F, F3);
  elr3_kernel<<<(N * 4 + 255) / 256, 256, 0, stream>>>(feat, al3, ar3, el, er, N);
  edgew_kernel<<<nodeBlocks, 256, 0, stream>>>(rowptr, csr_src, el, er, wbufT, den, N, E);
  agg3_kernel<<<nodeBlocks, 256, 0, stream>>>(rowptr, csr_src, feat, wbufT, den, b3,
                                              (float*)d_out, N, E);
}

// Round 5
// 977.744 us; speedup vs baseline: 1.0816x; 1.0816x over previous
//
#include <hip/hip_runtime.h>
#include <hip/hip_bf16.h>

typedef unsigned short ushort;
typedef unsigned int uint;
typedef __attribute__((ext_vector_type(8))) short short8;
typedef __attribute__((ext_vector_type(4))) float floatx4;
typedef __attribute__((ext_vector_type(2))) float floatx2;

#define NEG_SLOPE 0.2f

__device__ __forceinline__ float bu2f(ushort u) {
  uint t = ((uint)u) << 16;
  return __uint_as_float(t);
}
__device__ __forceinline__ ushort f2bu(float f) {
  __hip_bfloat16 h = __float2bfloat16(f);
  return *(ushort*)&h;
}
__device__ __forceinline__ float lo2f(uint u) { return __uint_as_float(u << 16); }
__device__ __forceinline__ float hi2f(uint u) { return __uint_as_float(u & 0xffff0000u); }
__device__ __forceinline__ float lrelu(float e) { return (e > 0.f) ? e : NEG_SLOPE * e; }
__device__ __forceinline__ float bperm(int byteaddr, float v) {
  return __uint_as_float((uint)__builtin_amdgcn_ds_bpermute(byteaddr, (int)__float_as_uint(v)));
}

// ---------------- CSR build ----------------
__global__ void zero_int_kernel(int* __restrict__ p, int n) {
  int i = blockIdx.x * blockDim.x + threadIdx.x;
  if (i < n) p[i] = 0;
}

__global__ void hist_kernel(const int* __restrict__ dst, int* __restrict__ deg, int E) {
  int e = blockIdx.x * blockDim.x + threadIdx.x;
  if (e < E) atomicAdd(&deg[dst[e]], 1);
}

__global__ void scan1_kernel(const int* __restrict__ deg, int* __restrict__ part,
                             int* __restrict__ bsums, int n) {
  __shared__ int sdata[256];
  int t = threadIdx.x;
  int base = blockIdx.x * 1024;
  int v[4]; int s = 0;
#pragma unroll
  for (int j = 0; j < 4; ++j) {
    int idx = base + t * 4 + j;
    v[j] = (idx < n) ? deg[idx] : 0;
    s += v[j];
  }
  sdata[t] = s;
  __syncthreads();
  for (int off = 1; off < 256; off <<= 1) {
    int x = 0;
    if (t >= off) x = sdata[t - off];
    __syncthreads();
    if (t >= off) sdata[t] += x;
    __syncthreads();
  }
  if (t == 255) bsums[blockIdx.x] = sdata[255];
  int run = (t > 0) ? sdata[t - 1] : 0;
#pragma unroll
  for (int j = 0; j < 4; ++j) {
    int idx = base + t * 4 + j;
    if (idx < n) part[idx] = run;
    run += v[j];
  }
}

__global__ void scan2_kernel(int* __restrict__ bsums, int nb) {
  __shared__ int sdata[256];
  int t = threadIdx.x;
  sdata[t] = (t < nb) ? bsums[t] : 0;
  __syncthreads();
  for (int off = 1; off < 256; off <<= 1) {
    int x = 0;
    if (t >= off) x = sdata[t - off];
    __syncthreads();
    if (t >= off) sdata[t] += x;
    __syncthreads();
  }
  if (t < nb) bsums[t] = (t > 0) ? sdata[t - 1] : 0;
}

__global__ void scan3_kernel(const int* __restrict__ part, const int* __restrict__ bsums,
                             int* __restrict__ rowptr, int* __restrict__ cursor,
                             int n, int Etot) {
  int i = blockIdx.x * blockDim.x + threadIdx.x;
  if (i < n) {
    int v = part[i] + bsums[i >> 10];
    rowptr[i] = v;
    cursor[i] = v;
  }
  if (i == 0) rowptr[n] = Etot;
}

__global__ void scatter_kernel(const int* __restrict__ src, const int* __restrict__ dst,
                               int* __restrict__ cursor, int* __restrict__ csr_src, int E) {
  int e = blockIdx.x * blockDim.x + threadIdx.x;
  if (e < E) {
    int pos = atomicAdd(&cursor[dst[e]], 1);
    csr_src[pos] = src[e];
  }
}

// ---------------- splits ----------------
__global__ void splitx_kernel(const float* __restrict__ x, ushort* __restrict__ xhi,
                              ushort* __restrict__ xlo, int n) {
  int base = (blockIdx.x * blockDim.x + threadIdx.x) * 4;
  if (base >= n) return;
  float4 a = *(const float4*)(x + base);
  float v[4] = {a.x, a.y, a.z, a.w};
  ushort hi[4], lo[4];
#pragma unroll
  for (int j = 0; j < 4; ++j) {
    hi[j] = f2bu(v[j]);
    lo[j] = f2bu(v[j] - bu2f(hi[j]));
  }
  uint2 ho, loo;
  ho.x = (uint)hi[0] | ((uint)hi[1] << 16);
  ho.y = (uint)hi[2] | ((uint)hi[3] << 16);
  loo.x = (uint)lo[0] | ((uint)lo[1] << 16);
  loo.y = (uint)lo[2] | ((uint)lo[3] << 16);
  *(uint2*)(xhi + base) = ho;
  *(uint2*)(xlo + base) = loo;
}

__global__ void splitW_kernel(const float* __restrict__ W, ushort* __restrict__ WtH,
                              ushort* __restrict__ WtL, int K, int Nc) {
  int idx = blockIdx.x * blockDim.x + threadIdx.x;
  if (idx >= K * Nc) return;
  int n = idx / K, k = idx - n * K;
  float w = W[(size_t)k * Nc + n];
  ushort hi = f2bu(w);
  WtH[idx] = hi;
  WtL[idx] = f2bu(w - bu2f(hi));
}

// ---------------- split-bf16 MFMA GEMM ----------------
#define GBM 128
#define GBN 64
#define GBK 32
#define SA 40

__global__ __launch_bounds__(256) void gemm_split_kernel(
    const ushort* __restrict__ Ah, const ushort* __restrict__ Al,
    const ushort* __restrict__ Bh, const ushort* __restrict__ Bl,
    ushort* __restrict__ C, int M, int K, int Nc) {
  __shared__ ushort AsH[GBM * SA];
  __shared__ ushort AsL[GBM * SA];
  __shared__ ushort BsH[GBN * SA];
  __shared__ ushort BsL[GBN * SA];
  int tid = threadIdx.x;
  int lane = tid & 63;
  int wave = tid >> 6;
  int wm = wave & 1, wn = wave >> 1;
  int rowBase = blockIdx.y * GBM;
  int colBase = blockIdx.x * GBN;
  int q = lane >> 4;
  int ln = lane & 15;

  floatx4 acc[4][2] = {};

  for (int k0 = 0; k0 < K; k0 += GBK) {
#pragma unroll
    for (int it = 0; it < 2; ++it) {
      int i = tid + it * 256;
      int r = i >> 2, seg = i & 3;
      int grow = rowBase + r;
      uint4 vh = {0u, 0u, 0u, 0u}, vl = {0u, 0u, 0u, 0u};
      if (grow < M) {
        size_t off = (size_t)grow * K + k0 + seg * 8;
        vh = *(const uint4*)(Ah + off);
        vl = *(const uint4*)(Al + off);
      }
      *(uint4*)&AsH[r * SA + seg * 8] = vh;
      *(uint4*)&AsL[r * SA + seg * 8] = vl;
    }
    {
      int n = tid >> 2, seg = tid & 3;
      int gcol = colBase + n;
      uint4 vh = {0u, 0u, 0u, 0u}, vl = {0u, 0u, 0u, 0u};
      if (gcol < Nc) {
        size_t off = (size_t)gcol * K + k0 + seg * 8;
        vh = *(const uint4*)(Bh + off);
        vl = *(const uint4*)(Bl + off);
      }
      *(uint4*)&BsH[n * SA + seg * 8] = vh;
      *(uint4*)&BsL[n * SA + seg * 8] = vl;
    }
    __syncthreads();
    short8 afH[4], afL[4], bfH[2], bfL[2];
#pragma unroll
    for (int mt = 0; mt < 4; ++mt) {
      int r = (wm * 64 + mt * 16 + ln) * SA + q * 8;
      afH[mt] = *(const short8*)&AsH[r];
      afL[mt] = *(const short8*)&AsL[r];
    }
#pragma unroll
    for (int nt = 0; nt < 2; ++nt) {
      int r = (wn * 32 + nt * 16 + ln) * SA + q * 8;
      bfH[nt] = *(const short8*)&BsH[r];
      bfL[nt] = *(const short8*)&BsL[r];
    }
#pragma unroll
    for (int mt = 0; mt < 4; ++mt)
#pragma unroll
      for (int nt = 0; nt < 2; ++nt) {
        acc[mt][nt] = __builtin_amdgcn_mfma_f32_16x16x32_bf16(afH[mt], bfH[nt], acc[mt][nt], 0, 0, 0);
        acc[mt][nt] = __builtin_amdgcn_mfma_f32_16x16x32_bf16(afH[mt], bfL[nt], acc[mt][nt], 0, 0, 0);
        acc[mt][nt] = __builtin_amdgcn_mfma_f32_16x16x32_bf16(afL[mt], bfH[nt], acc[mt][nt], 0, 0, 0);
      }
    __syncthreads();
  }
#pragma unroll
  for (int mt = 0; mt < 4; ++mt) {
#pragma unroll
    for (int nt = 0; nt < 2; ++nt) {
      int col = colBase + wn * 32 + nt * 16 + ln;
      if (col < Nc) {
#pragma unroll
        for (int r = 0; r < 4; ++r) {
          int row = rowBase + wm * 64 + mt * 16 + q * 4 + r;
          if (row < M) C[(size_t)row * Nc + col] = f2bu(acc[mt][nt][r]);
        }
      }
    }
  }
}

// ---------------- el/er layer 1/2 (Dh=32, F=128): vectorized uint4 loads ----------------
__global__ void elr128_kernel(const ushort* __restrict__ feat, const float* __restrict__ al,
                              const float* __restrict__ ar, float* __restrict__ el,
                              float* __restrict__ er, int N) {
  int g = blockIdx.x * blockDim.x + threadIdx.x;
  if (g >= N * 4) return;
  int n = g >> 2, h = g & 3;
  const uint4* fp = (const uint4*)(feat + (size_t)n * 128 + h * 32);
  const float* alp = al + h * 32;
  const float* arp = ar + h * 32;
  float sl = 0.f, sr = 0.f;
#pragma unroll
  for (int b = 0; b < 4; ++b) {
    uint4 u = fp[b];
    uint w[4] = {u.x, u.y, u.z, u.w};
#pragma unroll
    for (int j = 0; j < 4; ++j) {
      int d = b * 8 + j * 2;
      float f0 = lo2f(w[j]), f1 = hi2f(w[j]);
      sl += f0 * alp[d] + f1 * alp[d + 1];
      sr += f0 * arp[d] + f1 * arp[d + 1];
    }
  }
  el[g] = sl;
  er[g] = sr;
}

// ---------------- el/er layer 3 (Dh=47, F=188): scalar ----------------
__global__ void elr3_kernel(const ushort* __restrict__ feat, const float* __restrict__ al,
                            const float* __restrict__ ar, float* __restrict__ el,
                            float* __restrict__ er, int N) {
  int g = blockIdx.x * blockDim.x + threadIdx.x;
  if (g >= N * 4) return;
  int n = g >> 2, h = g & 3;
  const ushort* fp = feat + (size_t)n * 188 + h * 47;
  float sl = 0.f, sr = 0.f;
  for (int d = 0; d < 47; ++d) {
    float f = bu2f(fp[d]);
    sl += f * al[h * 47 + d];
    sr += f * ar[h * 47 + d];
  }
  el[g] = sl;
  er[g] = sr;
}

// ---------------- fused layer 1/2 aggregation, wave/node ----------------
// Round-3 structure + (a) full 16-unroll fast path with constant-folded
// bpermute offsets, (b) per-chunk den tree (densum), (c) pk_fma via float2.
__global__ __launch_bounds__(256, 4) void agg128_kernel(
    const int* __restrict__ rowptr, const int* __restrict__ csr_src,
    const ushort* __restrict__ feat, const float* __restrict__ el,
    const float* __restrict__ er, const float* __restrict__ bias,
    ushort* __restrict__ hhi, ushort* __restrict__ hlo, int N) {
  int lane = threadIdx.x & 63;
  int v = blockIdx.x * 4 + (threadIdx.x >> 6);
  if (v >= N) return;
  float4 er4 = *(const float4*)(er + (size_t)v * 4);
  int r0 = rowptr[v], r1 = rowptr[v + 1];
  int hh = lane & 3;
  float eh = (hh == 0) ? er4.x : (hh == 1) ? er4.y : (hh == 2) ? er4.z : er4.w;
  int hf = lane >> 4;  // head owning features 2*lane, 2*lane+1
  int hf4 = hf * 4;    // bpermute byte base
  const uint* fb = (const uint*)feat;
  floatx2 c01 = {0.f, 0.f};
  float densum = 0.f;
  for (int i0 = r0; i0 < r1; i0 += 16) {
    int i = i0 + (lane >> 2);
    int sv = 0;
    float xv = 0.f;
    if (i < r1) {
      sv = csr_src[i];
      xv = __expf(lrelu(el[(size_t)sv * 4 + hh] + eh));
    }
    // chunk denominator: butterfly sums lanes ≡ (mod 4) = one head's 16 slots
    float ds = xv;
    ds += __shfl_xor(ds, 4);
    ds += __shfl_xor(ds, 8);
    ds += __shfl_xor(ds, 16);
    ds += __shfl_xor(ds, 32);
    densum += ds;
    int cnt = r1 - i0;
    if (cnt > 16) cnt = 16;
    if (cnt == 16) {
#pragma unroll
      for (int j = 0; j < 16; ++j) {
        int s = __builtin_amdgcn_readlane(sv, 4 * j);
        float x = bperm(16 * j + hf4, xv);
        uint u = fb[((size_t)(uint)s << 6) + lane];
        floatx2 f = {lo2f(u), hi2f(u)};
        floatx2 xx = {x, x};
        c01 += xx * f;
      }
    } else {
      for (int j = 0; j < cnt; ++j) {
        int s = __builtin_amdgcn_readlane(sv, 4 * j);
        float x = __shfl(xv, 4 * j + hf);
        uint u = fb[((size_t)(uint)s << 6) + lane];
        floatx2 f = {lo2f(u), hi2f(u)};
        floatx2 xx = {x, x};
        c01 += xx * f;
      }
    }
  }
  float den = __shfl(densum, hf);  // lane hf holds head-hf total
  float o0 = (den > 0.f) ? c01.x / den : 0.f;
  float o1 = (den > 0.f) ? c01.y / den : 0.f;
  o0 = fmaxf(o0 + bias[2 * lane], 0.f);
  o1 = fmaxf(o1 + bias[2 * lane + 1], 0.f);
  ushort h0 = f2bu(o0), h1 = f2bu(o1);
  ushort l0 = f2bu(o0 - bu2f(h0)), l1 = f2bu(o1 - bu2f(h1));
  ((uint*)hhi)[(size_t)v * 64 + lane] = (uint)h0 | ((uint)h1 << 16);
  ((uint*)hlo)[(size_t)v * 64 + lane] = (uint)l0 | ((uint)l1 << 16);
}

// ---------------- fused layer 3 aggregation + bias + head-mean + log_softmax ----------
__global__ __launch_bounds__(256, 4) void agg3_kernel(
    const int* __restrict__ rowptr, const int* __restrict__ csr_src,
    const ushort* __restrict__ feat, const float* __restrict__ el,
    const float* __restrict__ er, const float* __restrict__ bias,
    float* __restrict__ out, int N) {
  __shared__ float svm[4][188];
  int lane = threadIdx.x & 63;
  int w = threadIdx.x >> 6;
  int v = blockIdx.x * 4 + w;
  bool valid = (v < N);
  float4 er4 = {0.f, 0.f, 0.f, 0.f};
  int r0 = 0, r1 = 0;
  if (valid) {
    er4 = *(const float4*)(er + (size_t)v * 4);
    r0 = rowptr[v];
    r1 = rowptr[v + 1];
  }
  int hh = lane & 3;
  float eh = (hh == 0) ? er4.x : (hh == 1) ? er4.y : (hh == 2) ? er4.z : er4.w;
  // lane owns features 2l,2l+1 and (lanes<30) 128+2l,129+2l
  int fa = 2 * lane, fbi = 2 * lane + 1;
  int fc = 128 + 2 * lane, fd = 129 + 2 * lane;
  bool hasC = (fd < 188);
  int ha = fa / 47, hb = fbi / 47;
  int hc = hasC ? fc / 47 : 3, hd = hasC ? fd / 47 : 3;
  int ha4 = ha * 4, hb4 = hb * 4, hc4 = hc * 4, hd4 = hd * 4;
  int off2 = hasC ? 64 : 0;  // branchless: inactive lanes re-read row half 0 (same lines)
  const uint* fpb = (const uint*)feat;  // feat row: 94 uints
  floatx2 cab = {0.f, 0.f}, ccd = {0.f, 0.f};
  float densum = 0.f;
  for (int i0 = r0; i0 < r1; i0 += 16) {
    int i = i0 + (lane >> 2);
    int sv = 0;
    float xv = 0.f;
    if (i < r1) {
      sv = csr_src[i];
      xv = __expf(lrelu(el[(size_t)sv * 4 + hh] + eh));
    }
    float ds = xv;
    ds += __shfl_xor(ds, 4);
    ds += __shfl_xor(ds, 8);
    ds += __shfl_xor(ds, 16);
    ds += __shfl_xor(ds, 32);
    densum += ds;
    int cnt = r1 - i0;
    if (cnt > 16) cnt = 16;
    if (cnt == 16) {
#pragma unroll
      for (int j = 0; j < 16; ++j) {
        int s = __builtin_amdgcn_readlane(sv, 4 * j);
        float xa = bperm(16 * j + ha4, xv);
        float xb = bperm(16 * j + hb4, xv);
        float xc = bperm(16 * j + hc4, xv);
        float xd = bperm(16 * j + hd4, xv);
        const uint* fr = fpb + (size_t)(uint)s * 94;
        uint u0 = fr[lane];
        uint u1 = fr[off2 + lane];
        floatx2 xab = {xa, xb}, xcd = {xc, xd};
        floatx2 f0 = {lo2f(u0), hi2f(u0)};
        floatx2 f1 = {lo2f(u1), hi2f(u1)};
        cab += xab * f0;
        ccd += xcd * f1;
      }
    } else {
      for (int j = 0; j < cnt; ++j) {
        int s = __builtin_amdgcn_readlane(sv, 4 * j);
        float xa = __shfl(xv, 4 * j + ha);
        float xb = __shfl(xv, 4 * j + hb);
        float xc = __shfl(xv, 4 * j + hc);
        float xd = __shfl(xv, 4 * j + hd);
        const uint* fr = fpb + (size_t)(uint)s * 94;
        uint u0 = fr[lane];
        uint u1 = fr[off2 + lane];
        floatx2 xab = {xa, xb}, xcd = {xc, xd};
        floatx2 f0 = {lo2f(u0), hi2f(u0)};
        floatx2 f1 = {lo2f(u1), hi2f(u1)};
        cab += xab * f0;
        ccd += xcd * f1;
      }
    }
  }
  float da = __shfl(densum, ha);
  float db = __shfl(densum, hb);
  float dc = __shfl(densum, hc);
  float dd = __shfl(densum, hd);
  float oa = ((da > 0.f) ? cab.x / da : 0.f) + bias[fa];
  float ob = ((db > 0.f) ? cab.y / db : 0.f) + bias[fbi];
  if (valid) {
    svm[w][fa] = oa;
    svm[w][fbi] = ob;
    if (hasC) {
      float oc = ((dc > 0.f) ? ccd.x / dc : 0.f) + bias[fc];
      float od = ((dd > 0.f) ? ccd.y / dd : 0.f) + bias[fd];
      svm[w][fc] = oc;
      svm[w][fd] = od;
    }
  }
  __syncthreads();
  float val = -1e30f;
  if (valid && lane < 47)
    val = 0.25f * (svm[w][lane] + svm[w][47 + lane] + svm[w][94 + lane] + svm[w][141 + lane]);
  float mx = val;
#pragma unroll
  for (int off = 32; off > 0; off >>= 1) mx = fmaxf(mx, __shfl_xor(mx, off));
  float ex = (lane < 47) ? __expf(val - mx) : 0.f;
  float sum = ex;
#pragma unroll
  for (int off = 32; off > 0; off >>= 1) sum += __shfl_xor(sum, off);
  float res = val - mx - logf(sum);
  if (valid && lane < 47) out[(size_t)v * 47 + lane] = res;
}

// ---------------- host orchestration ----------------
extern "C" void kernel_launch(void* const* d_in, const int* in_sizes, int n_in,
                              void* d_out, int out_size, void* d_ws, size_t ws_size,
                              hipStream_t stream) {
  const int N = 100000, E = 1600000, IN = 256;
  const int F = 128;   // H*D
  const int F3 = 188;  // H*C

  const float* x = (const float*)d_in[0];
  const int* src = (const int*)d_in[1];
  const int* dst = (const int*)d_in[2];
  const float* W1 = (const float*)d_in[3];
  const float* al1 = (const float*)d_in[4];
  const float* ar1 = (const float*)d_in[5];
  const float* b1 = (const float*)d_in[6];
  const float* W2 = (const float*)d_in[7];
  const float* al2 = (const float*)d_in[8];
  const float* ar2 = (const float*)d_in[9];
  const float* b2 = (const float*)d_in[10];
  const float* W3 = (const float*)d_in[11];
  const float* al3 = (const float*)d_in[12];
  const float* ar3 = (const float*)d_in[13];
  const float* b3 = (const float*)d_in[14];

  char* p = (char*)d_ws;
  auto alloc = [&](size_t bytes) -> char* {
    char* r = p;
    p += (bytes + 255) & ~(size_t)255;
    return r;
  };
  ushort* xhi = (ushort*)alloc((size_t)N * IN * sizeof(ushort));
  ushort* xlo = (ushort*)alloc((size_t)N * IN * sizeof(ushort));
  ushort* feat = (ushort*)alloc((size_t)N * F3 * sizeof(ushort));
  ushort* Wt1h = (ushort*)alloc((size_t)F * IN * sizeof(ushort));
  ushort* Wt1l = (ushort*)alloc((size_t)F * IN * sizeof(ushort));
  ushort* Wt2h = (ushort*)alloc((size_t)F * F * sizeof(ushort));
  ushort* Wt2l = (ushort*)alloc((size_t)F * F * sizeof(ushort));
  ushort* Wt3h = (ushort*)alloc((size_t)F3 * F * sizeof(ushort));
  ushort* Wt3l = (ushort*)alloc((size_t)F3 * F * sizeof(ushort));
  float* el = (float*)alloc((size_t)N * 4 * sizeof(float));
  float* er = (float*)alloc((size_t)N * 4 * sizeof(float));
  int* deg = (int*)alloc((size_t)N * sizeof(int));
  int* part = (int*)alloc((size_t)N * sizeof(int));
  int* bsums = (int*)alloc(256 * sizeof(int));
  int* rowptr = (int*)alloc((size_t)(N + 1) * sizeof(int));
  int* cursor = (int*)alloc((size_t)N * sizeof(int));
  int* csr_src = (int*)alloc((size_t)E * sizeof(int));

  // h (layers 2/3 input) aliases the x split buffers — x is consumed by the
  // layer-1 GEMM before agg128 overwrites these (single-stream ordering).
  ushort* hhi = xhi;
  ushort* hlo = xlo;

  // ---- CSR build ----
  zero_int_kernel<<<(N + 255) / 256, 256, 0, stream>>>(deg, N);
  hist_kernel<<<(E + 255) / 256, 256, 0, stream>>>(dst, deg, E);
  int nb = (N + 1023) / 1024;
  scan1_kernel<<<nb, 256, 0, stream>>>(deg, part, bsums, N);
  scan2_kernel<<<1, 256, 0, stream>>>(bsums, nb);
  scan3_kernel<<<(N + 255) / 256, 256, 0, stream>>>(part, bsums, rowptr, cursor, N, E);
  scatter_kernel<<<(E + 255) / 256, 256, 0, stream>>>(src, dst, cursor, csr_src, E);

  // ---- splits ----
  splitx_kernel<<<(N * IN / 4 + 255) / 256, 256, 0, stream>>>(x, xhi, xlo, N * IN);
  splitW_kernel<<<(IN * F + 255) / 256, 256, 0, stream>>>(W1, Wt1h, Wt1l, IN, F);
  splitW_kernel<<<(F * F + 255) / 256, 256, 0, stream>>>(W2, Wt2h, Wt2l, F, F);
  splitW_kernel<<<(F * F3 + 255) / 256, 256, 0, stream>>>(W3, Wt3h, Wt3l, F, F3);

  int rowBlocks = (N + GBM - 1) / GBM;  // 782
  int nodeBlocks = (N + 3) / 4;

  // ---- layer 1: IN=256 -> 128 ----
  gemm_split_kernel<<<dim3(F / GBN, rowBlocks), 256, 0, stream>>>(
      xhi, xlo, Wt1h, Wt1l, feat, N, IN, F);
  elr128_kernel<<<(N * 4 + 255) / 256, 256, 0, stream>>>(feat, al1, ar1, el, er, N);
  agg128_kernel<<<nodeBlocks, 256, 0, stream>>>(rowptr, csr_src, feat, el, er, b1, hhi, hlo, N);

  // ---- layer 2: 128 -> 128 ----
  gemm_split_kernel<<<dim3(F / GBN, rowBlocks), 256, 0, stream>>>(
      hhi, hlo, Wt2h, Wt2l, feat, N, F, F);
  elr128_kernel<<<(N * 4 + 255) / 256, 256, 0, stream>>>(feat, al2, ar2, el, er, N);
  agg128_kernel<<<nodeBlocks, 256, 0, stream>>>(rowptr, csr_src, feat, el, er, b2, hhi, hlo, N);

  // ---- layer 3: 128 -> 188, fused epilogue ----
  gemm_split_kernel<<<dim3((F3 + GBN - 1) / GBN, rowBlocks), 256, 0, stream>>>(
      hhi, hlo, Wt3h, Wt3l, feat, N, F, F3);
  elr3_kernel<<<(N * 4 + 255) / 256, 256, 0, stream>>>(feat, al3, ar3, el, er, N);
  agg3_kernel<<<nodeBlocks, 256, 0, stream>>>(rowptr, csr_src, feat, el, er, b3,
                                              (float*)d_out, N);
}

// Round 7
// 926.091 us; speedup vs baseline: 1.1419x; 1.0558x over previous
//
#include <hip/hip_runtime.h>
#include <hip/hip_bf16.h>

typedef unsigned short ushort;
typedef unsigned int uint;
typedef __attribute__((ext_vector_type(8))) short short8;
typedef __attribute__((ext_vector_type(4))) float floatx4;
typedef __attribute__((ext_vector_type(2))) float floatx2;

#define NEG_SLOPE 0.2f

__device__ __forceinline__ float bu2f(ushort u) {
  uint t = ((uint)u) << 16;
  return __uint_as_float(t);
}
__device__ __forceinline__ ushort f2bu(float f) {
  __hip_bfloat16 h = __float2bfloat16(f);
  return *(ushort*)&h;
}
__device__ __forceinline__ float lo2f(uint u) { return __uint_as_float(u << 16); }
__device__ __forceinline__ float hi2f(uint u) { return __uint_as_float(u & 0xffff0000u); }
__device__ __forceinline__ float lrelu(float e) { return (e > 0.f) ? e : NEG_SLOPE * e; }
__device__ __forceinline__ float bperm(int byteaddr, float v) {
  return __uint_as_float((uint)__builtin_amdgcn_ds_bpermute(byteaddr, (int)__float_as_uint(v)));
}

// ---------------- CSR build ----------------
__global__ void zero_int_kernel(int* __restrict__ p, int n) {
  int i = blockIdx.x * blockDim.x + threadIdx.x;
  if (i < n) p[i] = 0;
}

__global__ void hist_kernel(const int* __restrict__ dst, int* __restrict__ deg, int E) {
  int e = blockIdx.x * blockDim.x + threadIdx.x;
  if (e < E) atomicAdd(&deg[dst[e]], 1);
}

__global__ void scan1_kernel(const int* __restrict__ deg, int* __restrict__ part,
                             int* __restrict__ bsums, int n) {
  __shared__ int sdata[256];
  int t = threadIdx.x;
  int base = blockIdx.x * 1024;
  int v[4]; int s = 0;
#pragma unroll
  for (int j = 0; j < 4; ++j) {
    int idx = base + t * 4 + j;
    v[j] = (idx < n) ? deg[idx] : 0;
    s += v[j];
  }
  sdata[t] = s;
  __syncthreads();
  for (int off = 1; off < 256; off <<= 1) {
    int x = 0;
    if (t >= off) x = sdata[t - off];
    __syncthreads();
    if (t >= off) sdata[t] += x;
    __syncthreads();
  }
  if (t == 255) bsums[blockIdx.x] = sdata[255];
  int run = (t > 0) ? sdata[t - 1] : 0;
#pragma unroll
  for (int j = 0; j < 4; ++j) {
    int idx = base + t * 4 + j;
    if (idx < n) part[idx] = run;
    run += v[j];
  }
}

__global__ void scan2_kernel(int* __restrict__ bsums, int nb) {
  __shared__ int sdata[256];
  int t = threadIdx.x;
  sdata[t] = (t < nb) ? bsums[t] : 0;
  __syncthreads();
  for (int off = 1; off < 256; off <<= 1) {
    int x = 0;
    if (t >= off) x = sdata[t - off];
    __syncthreads();
    if (t >= off) sdata[t] += x;
    __syncthreads();
  }
  if (t < nb) bsums[t] = (t > 0) ? sdata[t - 1] : 0;
}

__global__ void scan3_kernel(const int* __restrict__ part, const int* __restrict__ bsums,
                             int* __restrict__ rowptr, int* __restrict__ cursor,
                             int n, int Etot) {
  int i = blockIdx.x * blockDim.x + threadIdx.x;
  if (i < n) {
    int v = part[i] + bsums[i >> 10];
    rowptr[i] = v;
    cursor[i] = v;
  }
  if (i == 0) rowptr[n] = Etot;
}

__global__ void scatter_kernel(const int* __restrict__ src, const int* __restrict__ dst,
                               int* __restrict__ cursor, int* __restrict__ csr_src, int E) {
  int e = blockIdx.x * blockDim.x + threadIdx.x;
  if (e < E) {
    int pos = atomicAdd(&cursor[dst[e]], 1);
    csr_src[pos] = src[e];
  }
}

// ---------------- splits ----------------
__global__ void splitx_kernel(const float* __restrict__ x, ushort* __restrict__ xhi,
                              ushort* __restrict__ xlo, int n) {
  int base = (blockIdx.x * blockDim.x + threadIdx.x) * 4;
  if (base >= n) return;
  float4 a = *(const float4*)(x + base);
  float v[4] = {a.x, a.y, a.z, a.w};
  ushort hi[4], lo[4];
#pragma unroll
  for (int j = 0; j < 4; ++j) {
    hi[j] = f2bu(v[j]);
    lo[j] = f2bu(v[j] - bu2f(hi[j]));
  }
  uint2 ho, loo;
  ho.x = (uint)hi[0] | ((uint)hi[1] << 16);
  ho.y = (uint)hi[2] | ((uint)hi[3] << 16);
  loo.x = (uint)lo[0] | ((uint)lo[1] << 16);
  loo.y = (uint)lo[2] | ((uint)lo[3] << 16);
  *(uint2*)(xhi + base) = ho;
  *(uint2*)(xlo + base) = loo;
}

__global__ void splitW_kernel(const float* __restrict__ W, ushort* __restrict__ WtH,
                              ushort* __restrict__ WtL, int K, int Nc) {
  int idx = blockIdx.x * blockDim.x + threadIdx.x;
  if (idx >= K * Nc) return;
  int n = idx / K, k = idx - n * K;
  float w = W[(size_t)k * Nc + n];
  ushort hi = f2bu(w);
  WtH[idx] = hi;
  WtL[idx] = f2bu(w - bu2f(hi));
}

// ---------------- split-bf16 MFMA GEMM ----------------
#define GBM 128
#define GBN 64
#define GBK 32
#define SA 40

__global__ __launch_bounds__(256) void gemm_split_kernel(
    const ushort* __restrict__ Ah, const ushort* __restrict__ Al,
    const ushort* __restrict__ Bh, const ushort* __restrict__ Bl,
    ushort* __restrict__ C, int M, int K, int Nc) {
  __shared__ ushort AsH[GBM * SA];
  __shared__ ushort AsL[GBM * SA];
  __shared__ ushort BsH[GBN * SA];
  __shared__ ushort BsL[GBN * SA];
  int tid = threadIdx.x;
  int lane = tid & 63;
  int wave = tid >> 6;
  int wm = wave & 1, wn = wave >> 1;
  int rowBase = blockIdx.y * GBM;
  int colBase = blockIdx.x * GBN;
  int q = lane >> 4;
  int ln = lane & 15;

  floatx4 acc[4][2] = {};

  for (int k0 = 0; k0 < K; k0 += GBK) {
#pragma unroll
    for (int it = 0; it < 2; ++it) {
      int i = tid + it * 256;
      int r = i >> 2, seg = i & 3;
      int grow = rowBase + r;
      uint4 vh = {0u, 0u, 0u, 0u}, vl = {0u, 0u, 0u, 0u};
      if (grow < M) {
        size_t off = (size_t)grow * K + k0 + seg * 8;
        vh = *(const uint4*)(Ah + off);
        vl = *(const uint4*)(Al + off);
      }
      *(uint4*)&AsH[r * SA + seg * 8] = vh;
      *(uint4*)&AsL[r * SA + seg * 8] = vl;
    }
    {
      int n = tid >> 2, seg = tid & 3;
      int gcol = colBase + n;
      uint4 vh = {0u, 0u, 0u, 0u}, vl = {0u, 0u, 0u, 0u};
      if (gcol < Nc) {
        size_t off = (size_t)gcol * K + k0 + seg * 8;
        vh = *(const uint4*)(Bh + off);
        vl = *(const uint4*)(Bl + off);
      }
      *(uint4*)&BsH[n * SA + seg * 8] = vh;
      *(uint4*)&BsL[n * SA + seg * 8] = vl;
    }
    __syncthreads();
    short8 afH[4], afL[4], bfH[2], bfL[2];
#pragma unroll
    for (int mt = 0; mt < 4; ++mt) {
      int r = (wm * 64 + mt * 16 + ln) * SA + q * 8;
      afH[mt] = *(const short8*)&AsH[r];
      afL[mt] = *(const short8*)&AsL[r];
    }
#pragma unroll
    for (int nt = 0; nt < 2; ++nt) {
      int r = (wn * 32 + nt * 16 + ln) * SA + q * 8;
      bfH[nt] = *(const short8*)&BsH[r];
      bfL[nt] = *(const short8*)&BsL[r];
    }
#pragma unroll
    for (int mt = 0; mt < 4; ++mt)
#pragma unroll
      for (int nt = 0; nt < 2; ++nt) {
        acc[mt][nt] = __builtin_amdgcn_mfma_f32_16x16x32_bf16(afH[mt], bfH[nt], acc[mt][nt], 0, 0, 0);
        acc[mt][nt] = __builtin_amdgcn_mfma_f32_16x16x32_bf16(afH[mt], bfL[nt], acc[mt][nt], 0, 0, 0);
        acc[mt][nt] = __builtin_amdgcn_mfma_f32_16x16x32_bf16(afL[mt], bfH[nt], acc[mt][nt], 0, 0, 0);
      }
    __syncthreads();
  }
#pragma unroll
  for (int mt = 0; mt < 4; ++mt) {
#pragma unroll
    for (int nt = 0; nt < 2; ++nt) {
      int col = colBase + wn * 32 + nt * 16 + ln;
      if (col < Nc) {
#pragma unroll
        for (int r = 0; r < 4; ++r) {
          int row = rowBase + wm * 64 + mt * 16 + q * 4 + r;
          if (row < M) C[(size_t)row * Nc + col] = f2bu(acc[mt][nt][r]);
        }
      }
    }
  }
}

// ---------------- el/er layer 1/2 (Dh=32, F=128): vectorized uint4 loads ----------------
__global__ void elr128_kernel(const ushort* __restrict__ feat, const float* __restrict__ al,
                              const float* __restrict__ ar, float* __restrict__ el,
                              float* __restrict__ er, int N) {
  int g = blockIdx.x * blockDim.x + threadIdx.x;
  if (g >= N * 4) return;
  int n = g >> 2, h = g & 3;
  const uint4* fp = (const uint4*)(feat + (size_t)n * 128 + h * 32);
  const float* alp = al + h * 32;
  const float* arp = ar + h * 32;
  float sl = 0.f, sr = 0.f;
#pragma unroll
  for (int b = 0; b < 4; ++b) {
    uint4 u = fp[b];
    uint w[4] = {u.x, u.y, u.z, u.w};
#pragma unroll
    for (int j = 0; j < 4; ++j) {
      int d = b * 8 + j * 2;
      float f0 = lo2f(w[j]), f1 = hi2f(w[j]);
      sl += f0 * alp[d] + f1 * alp[d + 1];
      sr += f0 * arp[d] + f1 * arp[d + 1];
    }
  }
  el[g] = sl;
  er[g] = sr;
}

// ---------------- el/er layer 3 (Dh=47, F=188): scalar ----------------
__global__ void elr3_kernel(const ushort* __restrict__ feat, const float* __restrict__ al,
                            const float* __restrict__ ar, float* __restrict__ el,
                            float* __restrict__ er, int N) {
  int g = blockIdx.x * blockDim.x + threadIdx.x;
  if (g >= N * 4) return;
  int n = g >> 2, h = g & 3;
  const ushort* fp = feat + (size_t)n * 188 + h * 47;
  float sl = 0.f, sr = 0.f;
  for (int d = 0; d < 47; ++d) {
    float f = bu2f(fp[d]);
    sl += f * al[h * 47 + d];
    sr += f * ar[h * 47 + d];
  }
  el[g] = sl;
  er[g] = sr;
}

// ---------------- fused layer 1/2 aggregation, wave/node (round-5 text, verified) ------
__global__ __launch_bounds__(256, 4) void agg128_kernel(
    const int* __restrict__ rowptr, const int* __restrict__ csr_src,
    const ushort* __restrict__ feat, const float* __restrict__ el,
    const float* __restrict__ er, const float* __restrict__ bias,
    ushort* __restrict__ hhi, ushort* __restrict__ hlo, int N) {
  int lane = threadIdx.x & 63;
  int v = blockIdx.x * 4 + (threadIdx.x >> 6);
  if (v >= N) return;
  float4 er4 = *(const float4*)(er + (size_t)v * 4);
  int r0 = rowptr[v], r1 = rowptr[v + 1];
  int hh = lane & 3;
  float eh = (hh == 0) ? er4.x : (hh == 1) ? er4.y : (hh == 2) ? er4.z : er4.w;
  int hf = lane >> 4;  // head owning features 2*lane, 2*lane+1
  int hf4 = hf * 4;    // bpermute byte base
  const uint* fb = (const uint*)feat;
  floatx2 c01 = {0.f, 0.f};
  float densum = 0.f;
  for (int i0 = r0; i0 < r1; i0 += 16) {
    int i = i0 + (lane >> 2);
    int sv = 0;
    float xv = 0.f;
    if (i < r1) {
      sv = csr_src[i];
      xv = __expf(lrelu(el[(size_t)sv * 4 + hh] + eh));
    }
    // chunk denominator: butterfly sums lanes ≡ (mod 4) = one head's 16 slots
    float ds = xv;
    ds += __shfl_xor(ds, 4);
    ds += __shfl_xor(ds, 8);
    ds += __shfl_xor(ds, 16);
    ds += __shfl_xor(ds, 32);
    densum += ds;
    int cnt = r1 - i0;
    if (cnt > 16) cnt = 16;
    if (cnt == 16) {
#pragma unroll
      for (int j = 0; j < 16; ++j) {
        int s = __builtin_amdgcn_readlane(sv, 4 * j);
        float x = bperm(16 * j + hf4, xv);
        uint u = fb[((size_t)(uint)s << 6) + lane];
        floatx2 f = {lo2f(u), hi2f(u)};
        floatx2 xx = {x, x};
        c01 += xx * f;
      }
    } else {
      for (int j = 0; j < cnt; ++j) {
        int s = __builtin_amdgcn_readlane(sv, 4 * j);
        float x = __shfl(xv, 4 * j + hf);
        uint u = fb[((size_t)(uint)s << 6) + lane];
        floatx2 f = {lo2f(u), hi2f(u)};
        floatx2 xx = {x, x};
        c01 += xx * f;
      }
    }
  }
  float den = __shfl(densum, hf);  // lane hf holds head-hf total
  float o0 = (den > 0.f) ? c01.x / den : 0.f;
  float o1 = (den > 0.f) ? c01.y / den : 0.f;
  o0 = fmaxf(o0 + bias[2 * lane], 0.f);
  o1 = fmaxf(o1 + bias[2 * lane + 1], 0.f);
  ushort h0 = f2bu(o0), h1 = f2bu(o1);
  ushort l0 = f2bu(o0 - bu2f(h0)), l1 = f2bu(o1 - bu2f(h1));
  ((uint*)hhi)[(size_t)v * 64 + lane] = (uint)h0 | ((uint)h1 << 16);
  ((uint*)hlo)[(size_t)v * 64 + lane] = (uint)l0 | ((uint)l1 << 16);
}

// ---------------- fused layer 3 aggregation + bias + head-mean + log_softmax ----------
// Round-3 text, verified passing (per-edge den accumulation, divergent hasC branch).
__global__ __launch_bounds__(256) void agg3_kernel(
    const int* __restrict__ rowptr, const int* __restrict__ csr_src,
    const ushort* __restrict__ feat, const float* __restrict__ el,
    const float* __restrict__ er, const float* __restrict__ bias,
    float* __restrict__ out, int N) {
  __shared__ float svm[4][188];
  int lane = threadIdx.x & 63;
  int w = threadIdx.x >> 6;
  int v = blockIdx.x * 4 + w;
  bool valid = (v < N);
  float4 er4 = {0.f, 0.f, 0.f, 0.f};
  int r0 = 0, r1 = 0;
  if (valid) {
    er4 = *(const float4*)(er + (size_t)v * 4);
    r0 = rowptr[v];
    r1 = rowptr[v + 1];
  }
  int hh = lane & 3;
  float eh = (hh == 0) ? er4.x : (hh == 1) ? er4.y : (hh == 2) ? er4.z : er4.w;
  // lane owns features 2l,2l+1 and (lanes<30) 128+2l,129+2l
  int fa = 2 * lane, fbi = 2 * lane + 1;
  int fc = 128 + 2 * lane, fd = 129 + 2 * lane;
  bool hasC = (fd < 188);
  int ha = fa / 47, hb = fbi / 47;
  int hc = hasC ? fc / 47 : 3, hd = hasC ? fd / 47 : 3;
  const uint* fpb = (const uint*)feat;  // feat row: 94 uints
  float aa = 0.f, ab = 0.f, ac = 0.f, ad = 0.f;
  float da = 0.f, db = 0.f, dc = 0.f, dd = 0.f;
  for (int i0 = r0; i0 < r1; i0 += 16) {
    int i = i0 + (lane >> 2);
    int sv = 0;
    float xv = 0.f;
    if (i < r1) {
      sv = csr_src[i];
      xv = __expf(lrelu(el[(size_t)sv * 4 + hh] + eh));
    }
    int cnt = r1 - i0;
    if (cnt > 16) cnt = 16;
#pragma unroll 2
    for (int j = 0; j < cnt; ++j) {
      int s = __builtin_amdgcn_readlane(sv, j * 4);
      float xa = __shfl(xv, j * 4 + ha);
      float xb = __shfl(xv, j * 4 + hb);
      const uint* fr = fpb + (size_t)(uint)s * 94;
      uint u0 = fr[lane];
      da += xa; db += xb;
      aa += xa * lo2f(u0);
      ab += xb * hi2f(u0);
      if (hasC) {
        float xc = __shfl(xv, j * 4 + hc);
        float xd = __shfl(xv, j * 4 + hd);
        uint u1 = fr[64 + lane];
        dc += xc; dd += xd;
        ac += xc * lo2f(u1);
        ad += xd * hi2f(u1);
      }
    }
  }
  float oa = ((da > 0.f) ? aa / da : 0.f) + bias[fa];
  float ob = ((db > 0.f) ? ab / db : 0.f) + bias[fbi];
  if (valid) {
    svm[w][fa] = oa;
    svm[w][fbi] = ob;
    if (hasC) {
      float oc = ((dc > 0.f) ? ac / dc : 0.f) + bias[fc];
      float od = ((dd > 0.f) ? ad / dd : 0.f) + bias[fd];
      svm[w][fc] = oc;
      svm[w][fd] = od;
    }
  }
  __syncthreads();
  float val = -1e30f;
  if (valid && lane < 47)
    val = 0.25f * (svm[w][lane] + svm[w][47 + lane] + svm[w][94 + lane] + svm[w][141 + lane]);
  float mx = val;
#pragma unroll
  for (int off = 32; off > 0; off >>= 1) mx = fmaxf(mx, __shfl_xor(mx, off));
  float ex = (lane < 47) ? __expf(val - mx) : 0.f;
  float sum = ex;
#pragma unroll
  for (int off = 32; off > 0; off >>= 1) sum += __shfl_xor(sum, off);
  float res = val - mx - logf(sum);
  if (valid && lane < 47) out[(size_t)v * 47 + lane] = res;
}

// ---------------- host orchestration ----------------
extern "C" void kernel_launch(void* const* d_in, const int* in_sizes, int n_in,
                              void* d_out, int out_size, void* d_ws, size_t ws_size,
                              hipStream_t stream) {
  const int N = 100000, E = 1600000, IN = 256;
  const int F = 128;   // H*D
  const int F3 = 188;  // H*C

  const float* x = (const float*)d_in[0];
  const int* src = (const int*)d_in[1];
  const int* dst = (const int*)d_in[2];
  const float* W1 = (const float*)d_in[3];
  const float* al1 = (const float*)d_in[4];
  const float* ar1 = (const float*)d_in[5];
  const float* b1 = (const float*)d_in[6];
  const float* W2 = (const float*)d_in[7];
  const float* al2 = (const float*)d_in[8];
  const float* ar2 = (const float*)d_in[9];
  const float* b2 = (const float*)d_in[10];
  const float* W3 = (const float*)d_in[11];
  const float* al3 = (const float*)d_in[12];
  const float* ar3 = (const float*)d_in[13];
  const float* b3 = (const float*)d_in[14];

  char* p = (char*)d_ws;
  auto alloc = [&](size_t bytes) -> char* {
    char* r = p;
    p += (bytes + 255) & ~(size_t)255;
    return r;
  };
  ushort* xhi = (ushort*)alloc((size_t)N * IN * sizeof(ushort));
  ushort* xlo = (ushort*)alloc((size_t)N * IN * sizeof(ushort));
  ushort* feat = (ushort*)alloc((size_t)N * F3 * sizeof(ushort));
  ushort* Wt1h = (ushort*)alloc((size_t)F * IN * sizeof(ushort));
  ushort* Wt1l = (ushort*)alloc((size_t)F * IN * sizeof(ushort));
  ushort* Wt2h = (ushort*)alloc((size_t)F * F * sizeof(ushort));
  ushort* Wt2l = (ushort*)alloc((size_t)F * F * sizeof(ushort));
  ushort* Wt3h = (ushort*)alloc((size_t)F3 * F * sizeof(ushort));
  ushort* Wt3l = (ushort*)alloc((size_t)F3 * F * sizeof(ushort));
  float* el = (float*)alloc((size_t)N * 4 * sizeof(float));
  float* er = (float*)alloc((size_t)N * 4 * sizeof(float));
  int* deg = (int*)alloc((size_t)N * sizeof(int));
  int* part = (int*)alloc((size_t)N * sizeof(int));
  int* bsums = (int*)alloc(256 * sizeof(int));
  int* rowptr = (int*)alloc((size_t)(N + 1) * sizeof(int));
  int* cursor = (int*)alloc((size_t)N * sizeof(int));
  int* csr_src = (int*)alloc((size_t)E * sizeof(int));

  // h (layers 2/3 input) aliases the x split buffers — x is consumed by the
  // layer-1 GEMM before agg128 overwrites these (single-stream ordering).
  ushort* hhi = xhi;
  ushort* hlo = xlo;

  // ---- CSR build ----
  zero_int_kernel<<<(N + 255) / 256, 256, 0, stream>>>(deg, N);
  hist_kernel<<<(E + 255) / 256, 256, 0, stream>>>(dst, deg, E);
  int nb = (N + 1023) / 1024;
  scan1_kernel<<<nb, 256, 0, stream>>>(deg, part, bsums, N);
  scan2_kernel<<<1, 256, 0, stream>>>(bsums, nb);
  scan3_kernel<<<(N + 255) / 256, 256, 0, stream>>>(part, bsums, rowptr, cursor, N, E);
  scatter_kernel<<<(E + 255) / 256, 256, 0, stream>>>(src, dst, cursor, csr_src, E);

  // ---- splits ----
  splitx_kernel<<<(N * IN / 4 + 255) / 256, 256, 0, stream>>>(x, xhi, xlo, N * IN);
  splitW_kernel<<<(IN * F + 255) / 256, 256, 0, stream>>>(W1, Wt1h, Wt1l, IN, F);
  splitW_kernel<<<(F * F + 255) / 256, 256, 0, stream>>>(W2, Wt2h, Wt2l, F, F);
  splitW_kernel<<<(F * F3 + 255) / 256, 256, 0, stream>>>(W3, Wt3h, Wt3l, F, F3);

  int rowBlocks = (N + GBM - 1) / GBM;  // 782
  int nodeBlocks = (N + 3) / 4;

  // ---- layer 1: IN=256 -> 128 ----
  gemm_split_kernel<<<dim3(F / GBN, rowBlocks), 256, 0, stream>>>(
      xhi, xlo, Wt1h, Wt1l, feat, N, IN, F);
  elr128_kernel<<<(N * 4 + 255) / 256, 256, 0, stream>>>(feat, al1, ar1, el, er, N);
  agg128_kernel<<<nodeBlocks, 256, 0, stream>>>(rowptr, csr_src, feat, el, er, b1, hhi, hlo, N);

  // ---- layer 2: 128 -> 128 ----
  gemm_split_kernel<<<dim3(F / GBN, rowBlocks), 256, 0, stream>>>(
      hhi, hlo, Wt2h, Wt2l, feat, N, F, F);
  elr128_kernel<<<(N * 4 + 255) / 256, 256, 0, stream>>>(feat, al2, ar2, el, er, N);
  agg128_kernel<<<nodeBlocks, 256, 0, stream>>>(rowptr, csr_src, feat, el, er, b2, hhi, hlo, N);

  // ---- layer 3: 128 -> 188, fused epilogue ----
  gemm_split_kernel<<<dim3((F3 + GBN - 1) / GBN, rowBlocks), 256, 0, stream>>>(
      hhi, hlo, Wt3h, Wt3l, feat, N, F, F3);
  elr3_kernel<<<(N * 4 + 255) / 256, 256, 0, stream>>>(feat, al3, ar3, el, er, N);
  agg3_kernel<<<nodeBlocks, 256, 0, stream>>>(rowptr, csr_src, feat, el, er, b3,
                                              (float*)d_out, N);
}

// Round 8
// 850.054 us; speedup vs baseline: 1.2441x; 1.0895x over previous
//
#include <hip/hip_runtime.h>
#include <hip/hip_bf16.h>

typedef unsigned short ushort;
typedef unsigned int uint;
typedef __attribute__((ext_vector_type(8))) short short8;
typedef __attribute__((ext_vector_type(4))) float floatx4;
typedef __attribute__((ext_vector_type(2))) float floatx2;

#define NEG_SLOPE 0.2f

__device__ __forceinline__ float bu2f(ushort u) {
  uint t = ((uint)u) << 16;
  return __uint_as_float(t);
}
__device__ __forceinline__ ushort f2bu(float f) {
  __hip_bfloat16 h = __float2bfloat16(f);
  return *(ushort*)&h;
}
__device__ __forceinline__ float lo2f(uint u) { return __uint_as_float(u << 16); }
__device__ __forceinline__ float hi2f(uint u) { return __uint_as_float(u & 0xffff0000u); }
__device__ __forceinline__ float lrelu(float e) { return (e > 0.f) ? e : NEG_SLOPE * e; }
__device__ __forceinline__ float bperm(int byteaddr, float v) {
  return __uint_as_float((uint)__builtin_amdgcn_ds_bpermute(byteaddr, (int)__float_as_uint(v)));
}

// ---------------- CSR build ----------------
__global__ void zero_int_kernel(int* __restrict__ p, int n) {
  int i = blockIdx.x * blockDim.x + threadIdx.x;
  if (i < n) p[i] = 0;
}

__global__ void hist_kernel(const int* __restrict__ dst, int* __restrict__ deg, int E) {
  int e = blockIdx.x * blockDim.x + threadIdx.x;
  if (e < E) atomicAdd(&deg[dst[e]], 1);
}

__global__ void scan1_kernel(const int* __restrict__ deg, int* __restrict__ part,
                             int* __restrict__ bsums, int n) {
  __shared__ int sdata[256];
  int t = threadIdx.x;
  int base = blockIdx.x * 1024;
  int v[4]; int s = 0;
#pragma unroll
  for (int j = 0; j < 4; ++j) {
    int idx = base + t * 4 + j;
    v[j] = (idx < n) ? deg[idx] : 0;
    s += v[j];
  }
  sdata[t] = s;
  __syncthreads();
  for (int off = 1; off < 256; off <<= 1) {
    int x = 0;
    if (t >= off) x = sdata[t - off];
    __syncthreads();
    if (t >= off) sdata[t] += x;
    __syncthreads();
  }
  if (t == 255) bsums[blockIdx.x] = sdata[255];
  int run = (t > 0) ? sdata[t - 1] : 0;
#pragma unroll
  for (int j = 0; j < 4; ++j) {
    int idx = base + t * 4 + j;
    if (idx < n) part[idx] = run;
    run += v[j];
  }
}

__global__ void scan2_kernel(int* __restrict__ bsums, int nb) {
  __shared__ int sdata[256];
  int t = threadIdx.x;
  sdata[t] = (t < nb) ? bsums[t] : 0;
  __syncthreads();
  for (int off = 1; off < 256; off <<= 1) {
    int x = 0;
    if (t >= off) x = sdata[t - off];
    __syncthreads();
    if (t >= off) sdata[t] += x;
    __syncthreads();
  }
  if (t < nb) bsums[t] = (t > 0) ? sdata[t - 1] : 0;
}

__global__ void scan3_kernel(const int* __restrict__ part, const int* __restrict__ bsums,
                             int* __restrict__ rowptr, int* __restrict__ cursor,
                             int n, int Etot) {
  int i = blockIdx.x * blockDim.x + threadIdx.x;
  if (i < n) {
    int v = part[i] + bsums[i >> 10];
    rowptr[i] = v;
    cursor[i] = v;
  }
  if (i == 0) rowptr[n] = Etot;
}

__global__ void scatter_kernel(const int* __restrict__ src, const int* __restrict__ dst,
                               int* __restrict__ cursor, int* __restrict__ csr_src, int E) {
  int e = blockIdx.x * blockDim.x + threadIdx.x;
  if (e < E) {
    int pos = atomicAdd(&cursor[dst[e]], 1);
    csr_src[pos] = src[e];
  }
}

// ---------------- splits ----------------
// A-low no longer consumed by the GEMM: emit hi only.
__global__ void splitx_kernel(const float* __restrict__ x, ushort* __restrict__ xhi, int n) {
  int base = (blockIdx.x * blockDim.x + threadIdx.x) * 4;
  if (base >= n) return;
  float4 a = *(const float4*)(x + base);
  float v[4] = {a.x, a.y, a.z, a.w};
  ushort hi[4];
#pragma unroll
  for (int j = 0; j < 4; ++j) hi[j] = f2bu(v[j]);
  uint2 ho;
  ho.x = (uint)hi[0] | ((uint)hi[1] << 16);
  ho.y = (uint)hi[2] | ((uint)hi[3] << 16);
  *(uint2*)(xhi + base) = ho;
}

__global__ void splitW_kernel(const float* __restrict__ W, ushort* __restrict__ WtH,
                              ushort* __restrict__ WtL, int K, int Nc) {
  int idx = blockIdx.x * blockDim.x + threadIdx.x;
  if (idx >= K * Nc) return;
  int n = idx / K, k = idx - n * K;
  float w = W[(size_t)k * Nc + n];
  ushort hi = f2bu(w);
  WtH[idx] = hi;
  WtL[idx] = f2bu(w - bu2f(hi));
}

// ---------------- split-bf16 MFMA GEMM: A(bf16) x (Bh + Bl) ----------------
// Dropped the Al·Bh term (error ~2^-9-relative, comparable to the bf16 output
// quantization): 2 MFMAs per tile instead of 3, no A-low staging (LDS 30->20KB).
#define GBM 128
#define GBN 64
#define GBK 32
#define SA 40

__global__ __launch_bounds__(256) void gemm_split_kernel(
    const ushort* __restrict__ A,
    const ushort* __restrict__ Bh, const ushort* __restrict__ Bl,
    ushort* __restrict__ C, int M, int K, int Nc) {
  __shared__ ushort As[GBM * SA];
  __shared__ ushort BsH[GBN * SA];
  __shared__ ushort BsL[GBN * SA];
  int tid = threadIdx.x;
  int lane = tid & 63;
  int wave = tid >> 6;
  int wm = wave & 1, wn = wave >> 1;
  int rowBase = blockIdx.y * GBM;
  int colBase = blockIdx.x * GBN;
  int q = lane >> 4;
  int ln = lane & 15;

  floatx4 acc[4][2] = {};

  for (int k0 = 0; k0 < K; k0 += GBK) {
#pragma unroll
    for (int it = 0; it < 2; ++it) {
      int i = tid + it * 256;
      int r = i >> 2, seg = i & 3;
      int grow = rowBase + r;
      uint4 vh = {0u, 0u, 0u, 0u};
      if (grow < M) {
        size_t off = (size_t)grow * K + k0 + seg * 8;
        vh = *(const uint4*)(A + off);
      }
      *(uint4*)&As[r * SA + seg * 8] = vh;
    }
    {
      int n = tid >> 2, seg = tid & 3;
      int gcol = colBase + n;
      uint4 vh = {0u, 0u, 0u, 0u}, vl = {0u, 0u, 0u, 0u};
      if (gcol < Nc) {
        size_t off = (size_t)gcol * K + k0 + seg * 8;
        vh = *(const uint4*)(Bh + off);
        vl = *(const uint4*)(Bl + off);
      }
      *(uint4*)&BsH[n * SA + seg * 8] = vh;
      *(uint4*)&BsL[n * SA + seg * 8] = vl;
    }
    __syncthreads();
    short8 af[4], bfH[2], bfL[2];
#pragma unroll
    for (int mt = 0; mt < 4; ++mt) {
      int r = (wm * 64 + mt * 16 + ln) * SA + q * 8;
      af[mt] = *(const short8*)&As[r];
    }
#pragma unroll
    for (int nt = 0; nt < 2; ++nt) {
      int r = (wn * 32 + nt * 16 + ln) * SA + q * 8;
      bfH[nt] = *(const short8*)&BsH[r];
      bfL[nt] = *(const short8*)&BsL[r];
    }
#pragma unroll
    for (int mt = 0; mt < 4; ++mt)
#pragma unroll
      for (int nt = 0; nt < 2; ++nt) {
        acc[mt][nt] = __builtin_amdgcn_mfma_f32_16x16x32_bf16(af[mt], bfH[nt], acc[mt][nt], 0, 0, 0);
        acc[mt][nt] = __builtin_amdgcn_mfma_f32_16x16x32_bf16(af[mt], bfL[nt], acc[mt][nt], 0, 0, 0);
      }
    __syncthreads();
  }
#pragma unroll
  for (int mt = 0; mt < 4; ++mt) {
#pragma unroll
    for (int nt = 0; nt < 2; ++nt) {
      int col = colBase + wn * 32 + nt * 16 + ln;
      if (col < Nc) {
#pragma unroll
        for (int r = 0; r < 4; ++r) {
          int row = rowBase + wm * 64 + mt * 16 + q * 4 + r;
          if (row < M) C[(size_t)row * Nc + col] = f2bu(acc[mt][nt][r]);
        }
      }
    }
  }
}

// ---------------- el/er layer 1/2 (Dh=32, F=128): vectorized uint4 loads ----------------
__global__ void elr128_kernel(const ushort* __restrict__ feat, const float* __restrict__ al,
                              const float* __restrict__ ar, float* __restrict__ el,
                              float* __restrict__ er, int N) {
  int g = blockIdx.x * blockDim.x + threadIdx.x;
  if (g >= N * 4) return;
  int n = g >> 2, h = g & 3;
  const uint4* fp = (const uint4*)(feat + (size_t)n * 128 + h * 32);
  const float* alp = al + h * 32;
  const float* arp = ar + h * 32;
  float sl = 0.f, sr = 0.f;
#pragma unroll
  for (int b = 0; b < 4; ++b) {
    uint4 u = fp[b];
    uint w[4] = {u.x, u.y, u.z, u.w};
#pragma unroll
    for (int j = 0; j < 4; ++j) {
      int d = b * 8 + j * 2;
      float f0 = lo2f(w[j]), f1 = hi2f(w[j]);
      sl += f0 * alp[d] + f1 * alp[d + 1];
      sr += f0 * arp[d] + f1 * arp[d + 1];
    }
  }
  el[g] = sl;
  er[g] = sr;
}

// ---------------- el/er layer 3 (Dh=47, F=188): scalar ----------------
__global__ void elr3_kernel(const ushort* __restrict__ feat, const float* __restrict__ al,
                            const float* __restrict__ ar, float* __restrict__ el,
                            float* __restrict__ er, int N) {
  int g = blockIdx.x * blockDim.x + threadIdx.x;
  if (g >= N * 4) return;
  int n = g >> 2, h = g & 3;
  const ushort* fp = feat + (size_t)n * 188 + h * 47;
  float sl = 0.f, sr = 0.f;
  for (int d = 0; d < 47; ++d) {
    float f = bu2f(fp[d]);
    sl += f * al[h * 47 + d];
    sr += f * ar[h * 47 + d];
  }
  el[g] = sl;
  er[g] = sr;
}

// ---------------- fused layer 1/2 aggregation, wave/node (round-5 core, hi-only out) ---
__global__ __launch_bounds__(256, 4) void agg128_kernel(
    const int* __restrict__ rowptr, const int* __restrict__ csr_src,
    const ushort* __restrict__ feat, const float* __restrict__ el,
    const float* __restrict__ er, const float* __restrict__ bias,
    ushort* __restrict__ hhi, int N) {
  int lane = threadIdx.x & 63;
  int v = blockIdx.x * 4 + (threadIdx.x >> 6);
  if (v >= N) return;
  float4 er4 = *(const float4*)(er + (size_t)v * 4);
  int r0 = rowptr[v], r1 = rowptr[v + 1];
  int hh = lane & 3;
  float eh = (hh == 0) ? er4.x : (hh == 1) ? er4.y : (hh == 2) ? er4.z : er4.w;
  int hf = lane >> 4;  // head owning features 2*lane, 2*lane+1
  int hf4 = hf * 4;    // bpermute byte base
  const uint* fb = (const uint*)feat;
  floatx2 c01 = {0.f, 0.f};
  float densum = 0.f;
  for (int i0 = r0; i0 < r1; i0 += 16) {
    int i = i0 + (lane >> 2);
    int sv = 0;
    float xv = 0.f;
    if (i < r1) {
      sv = csr_src[i];
      xv = __expf(lrelu(el[(size_t)sv * 4 + hh] + eh));
    }
    // chunk denominator: butterfly sums lanes ≡ (mod 4) = one head's 16 slots
    float ds = xv;
    ds += __shfl_xor(ds, 4);
    ds += __shfl_xor(ds, 8);
    ds += __shfl_xor(ds, 16);
    ds += __shfl_xor(ds, 32);
    densum += ds;
    int cnt = r1 - i0;
    if (cnt > 16) cnt = 16;
    if (cnt == 16) {
#pragma unroll
      for (int j = 0; j < 16; ++j) {
        int s = __builtin_amdgcn_readlane(sv, 4 * j);
        float x = bperm(16 * j + hf4, xv);
        uint u = fb[((size_t)(uint)s << 6) + lane];
        floatx2 f = {lo2f(u), hi2f(u)};
        floatx2 xx = {x, x};
        c01 += xx * f;
      }
    } else {
      for (int j = 0; j < cnt; ++j) {
        int s = __builtin_amdgcn_readlane(sv, 4 * j);
        float x = __shfl(xv, 4 * j + hf);
        uint u = fb[((size_t)(uint)s << 6) + lane];
        floatx2 f = {lo2f(u), hi2f(u)};
        floatx2 xx = {x, x};
        c01 += xx * f;
      }
    }
  }
  float den = __shfl(densum, hf);  // lane hf holds head-hf total
  float o0 = (den > 0.f) ? c01.x / den : 0.f;
  float o1 = (den > 0.f) ? c01.y / den : 0.f;
  o0 = fmaxf(o0 + bias[2 * lane], 0.f);
  o1 = fmaxf(o1 + bias[2 * lane + 1], 0.f);
  ushort h0 = f2bu(o0), h1 = f2bu(o1);
  ((uint*)hhi)[(size_t)v * 64 + lane] = (uint)h0 | ((uint)h1 << 16);
}

// ---------------- fused layer 3 aggregation + bias + head-mean + log_softmax ----------
// Round-3 rolled structure made CONVERGENT (off2 replaces the divergent hasC body)
// + the round-5-verified per-chunk den tree. Scalar fmaf accumulation.
__global__ __launch_bounds__(256) void agg3_kernel(
    const int* __restrict__ rowptr, const int* __restrict__ csr_src,
    const ushort* __restrict__ feat, const float* __restrict__ el,
    const float* __restrict__ er, const float* __restrict__ bias,
    float* __restrict__ out, int N) {
  __shared__ float svm[4][188];
  int lane = threadIdx.x & 63;
  int w = threadIdx.x >> 6;
  int v = blockIdx.x * 4 + w;
  bool valid = (v < N);
  float4 er4 = {0.f, 0.f, 0.f, 0.f};
  int r0 = 0, r1 = 0;
  if (valid) {
    er4 = *(const float4*)(er + (size_t)v * 4);
    r0 = rowptr[v];
    r1 = rowptr[v + 1];
  }
  int hh = lane & 3;
  float eh = (hh == 0) ? er4.x : (hh == 1) ? er4.y : (hh == 2) ? er4.z : er4.w;
  // lane owns features 2l,2l+1 and (lanes<30) 128+2l,129+2l
  int fa = 2 * lane, fbi = 2 * lane + 1;
  int fc = 128 + 2 * lane, fd = 129 + 2 * lane;
  bool hasC = (fd < 188);
  int ha = fa / 47, hb = fbi / 47;
  int hc = hasC ? fc / 47 : 3, hd = hasC ? fd / 47 : 3;
  int off2 = hasC ? 64 : 0;  // convergent: tail lanes re-read row half 0 (same lines)
  const uint* fpb = (const uint*)feat;  // feat row: 94 uints
  float aa = 0.f, ab = 0.f, ac = 0.f, ad = 0.f;
  float densum = 0.f;
  for (int i0 = r0; i0 < r1; i0 += 16) {
    int i = i0 + (lane >> 2);
    int sv = 0;
    float xv = 0.f;
    if (i < r1) {
      sv = csr_src[i];
      xv = __expf(lrelu(el[(size_t)sv * 4 + hh] + eh));
    }
    // chunk denominator tree (verified round 5)
    float ds = xv;
    ds += __shfl_xor(ds, 4);
    ds += __shfl_xor(ds, 8);
    ds += __shfl_xor(ds, 16);
    ds += __shfl_xor(ds, 32);
    densum += ds;
    int cnt = r1 - i0;
    if (cnt > 16) cnt = 16;
#pragma unroll 2
    for (int j = 0; j < cnt; ++j) {
      int s = __builtin_amdgcn_readlane(sv, j * 4);
      float xa = __shfl(xv, j * 4 + ha);
      float xb = __shfl(xv, j * 4 + hb);
      float xc = __shfl(xv, j * 4 + hc);
      float xd = __shfl(xv, j * 4 + hd);
      const uint* fr = fpb + (size_t)(uint)s * 94;
      uint u0 = fr[lane];
      uint u1 = fr[off2 + lane];
      aa = fmaf(xa, lo2f(u0), aa);
      ab = fmaf(xb, hi2f(u0), ab);
      ac = fmaf(xc, lo2f(u1), ac);
      ad = fmaf(xd, hi2f(u1), ad);
    }
  }
  float da = __shfl(densum, ha);
  float db = __shfl(densum, hb);
  float dc = __shfl(densum, hc);
  float dd = __shfl(densum, hd);
  float oa = ((da > 0.f) ? aa / da : 0.f) + bias[fa];
  float ob = ((db > 0.f) ? ab / db : 0.f) + bias[fbi];
  if (valid) {
    svm[w][fa] = oa;
    svm[w][fbi] = ob;
    if (hasC) {
      float oc = ((dc > 0.f) ? ac / dc : 0.f) + bias[fc];
      float od = ((dd > 0.f) ? ad / dd : 0.f) + bias[fd];
      svm[w][fc] = oc;
      svm[w][fd] = od;
    }
  }
  __syncthreads();
  float val = -1e30f;
  if (valid && lane < 47)
    val = 0.25f * (svm[w][lane] + svm[w][47 + lane] + svm[w][94 + lane] + svm[w][141 + lane]);
  float mx = val;
#pragma unroll
  for (int off = 32; off > 0; off >>= 1) mx = fmaxf(mx, __shfl_xor(mx, off));
  float ex = (lane < 47) ? __expf(val - mx) : 0.f;
  float sum = ex;
#pragma unroll
  for (int off = 32; off > 0; off >>= 1) sum += __shfl_xor(sum, off);
  float res = val - mx - logf(sum);
  if (valid && lane < 47) out[(size_t)v * 47 + lane] = res;
}

// ---------------- host orchestration ----------------
extern "C" void kernel_launch(void* const* d_in, const int* in_sizes, int n_in,
                              void* d_out, int out_size, void* d_ws, size_t ws_size,
                              hipStream_t stream) {
  const int N = 100000, E = 1600000, IN = 256;
  const int F = 128;   // H*D
  const int F3 = 188;  // H*C

  const float* x = (const float*)d_in[0];
  const int* src = (const int*)d_in[1];
  const int* dst = (const int*)d_in[2];
  const float* W1 = (const float*)d_in[3];
  const float* al1 = (const float*)d_in[4];
  const float* ar1 = (const float*)d_in[5];
  const float* b1 = (const float*)d_in[6];
  const float* W2 = (const float*)d_in[7];
  const float* al2 = (const float*)d_in[8];
  const float* ar2 = (const float*)d_in[9];
  const float* b2 = (const float*)d_in[10];
  const float* W3 = (const float*)d_in[11];
  const float* al3 = (const float*)d_in[12];
  const float* ar3 = (const float*)d_in[13];
  const float* b3 = (const float*)d_in[14];

  char* p = (char*)d_ws;
  auto alloc = [&](size_t bytes) -> char* {
    char* r = p;
    p += (bytes + 255) & ~(size_t)255;
    return r;
  };
  ushort* xhi = (ushort*)alloc((size_t)N * IN * sizeof(ushort));
  ushort* feat = (ushort*)alloc((size_t)N * F3 * sizeof(ushort));
  ushort* Wt1h = (ushort*)alloc((size_t)F * IN * sizeof(ushort));
  ushort* Wt1l = (ushort*)alloc((size_t)F * IN * sizeof(ushort));
  ushort* Wt2h = (ushort*)alloc((size_t)F * F * sizeof(ushort));
  ushort* Wt2l = (ushort*)alloc((size_t)F * F * sizeof(ushort));
  ushort* Wt3h = (ushort*)alloc((size_t)F3 * F * sizeof(ushort));
  ushort* Wt3l = (ushort*)alloc((size_t)F3 * F * sizeof(ushort));
  float* el = (float*)alloc((size_t)N * 4 * sizeof(float));
  float* er = (float*)alloc((size_t)N * 4 * sizeof(float));
  int* deg = (int*)alloc((size_t)N * sizeof(int));
  int* part = (int*)alloc((size_t)N * sizeof(int));
  int* bsums = (int*)alloc(256 * sizeof(int));
  int* rowptr = (int*)alloc((size_t)(N + 1) * sizeof(int));
  int* cursor = (int*)alloc((size_t)N * sizeof(int));
  int* csr_src = (int*)alloc((size_t)E * sizeof(int));

  // h (layers 2/3 input) aliases the x split buffer — x is consumed by the
  // layer-1 GEMM before agg128 overwrites it (single-stream ordering).
  ushort* hhi = xhi;

  // ---- CSR build ----
  zero_int_kernel<<<(N + 255) / 256, 256, 0, stream>>>(deg, N);
  hist_kernel<<<(E + 255) / 256, 256, 0, stream>>>(dst, deg, E);
  int nb = (N + 1023) / 1024;
  scan1_kernel<<<nb, 256, 0, stream>>>(deg, part, bsums, N);
  scan2_kernel<<<1, 256, 0, stream>>>(bsums, nb);
  scan3_kernel<<<(N + 255) / 256, 256, 0, stream>>>(part, bsums, rowptr, cursor, N, E);
  scatter_kernel<<<(E + 255) / 256, 256, 0, stream>>>(src, dst, cursor, csr_src, E);

  // ---- splits ----
  splitx_kernel<<<(N * IN / 4 + 255) / 256, 256, 0, stream>>>(x, xhi, N * IN);
  splitW_kernel<<<(IN * F + 255) / 256, 256, 0, stream>>>(W1, Wt1h, Wt1l, IN, F);
  splitW_kernel<<<(F * F + 255) / 256, 256, 0, stream>>>(W2, Wt2h, Wt2l, F, F);
  splitW_kernel<<<(F * F3 + 255) / 256, 256, 0, stream>>>(W3, Wt3h, Wt3l, F, F3);

  int rowBlocks = (N + GBM - 1) / GBM;  // 782
  int nodeBlocks = (N + 3) / 4;

  // ---- layer 1: IN=256 -> 128 ----
  gemm_split_kernel<<<dim3(F / GBN, rowBlocks), 256, 0, stream>>>(
      xhi, Wt1h, Wt1l, feat, N, IN, F);
  elr128_kernel<<<(N * 4 + 255) / 256, 256, 0, stream>>>(feat, al1, ar1, el, er, N);
  agg128_kernel<<<nodeBlocks, 256, 0, stream>>>(rowptr, csr_src, feat, el, er, b1, hhi, N);

  // ---- layer 2: 128 -> 128 ----
  gemm_split_kernel<<<dim3(F / GBN, rowBlocks), 256, 0, stream>>>(
      hhi, Wt2h, Wt2l, feat, N, F, F);
  elr128_kernel<<<(N * 4 + 255) / 256, 256, 0, stream>>>(feat, al2, ar2, el, er, N);
  agg128_kernel<<<nodeBlocks, 256, 0, stream>>>(rowptr, csr_src, feat, el, er, b2, hhi, N);

  // ---- layer 3: 128 -> 188, fused epilogue ----
  gemm_split_kernel<<<dim3((F3 + GBN - 1) / GBN, rowBlocks), 256, 0, stream>>>(
      hhi, Wt3h, Wt3l, feat, N, F, F3);
  elr3_kernel<<<(N * 4 + 255) / 256, 256, 0, stream>>>(feat, al3, ar3, el, er, N);
  agg3_kernel<<<nodeBlocks, 256, 0, stream>>>(rowptr, csr_src, feat, el, er, b3,
                                              (float*)d_out, N);
}

// Round 9
// 834.188 us; speedup vs baseline: 1.2678x; 1.0190x over previous
//
#include <hip/hip_runtime.h>
#include <hip/hip_bf16.h>

typedef unsigned short ushort;
typedef unsigned int uint;
typedef __attribute__((ext_vector_type(8))) short short8;
typedef __attribute__((ext_vector_type(4))) float floatx4;
typedef __attribute__((ext_vector_type(2))) float floatx2;

#define NEG_SLOPE 0.2f

__device__ __forceinline__ float bu2f(ushort u) {
  uint t = ((uint)u) << 16;
  return __uint_as_float(t);
}
__device__ __forceinline__ ushort f2bu(float f) {
  __hip_bfloat16 h = __float2bfloat16(f);
  return *(ushort*)&h;
}
__device__ __forceinline__ float lo2f(uint u) { return __uint_as_float(u << 16); }
__device__ __forceinline__ float hi2f(uint u) { return __uint_as_float(u & 0xffff0000u); }
__device__ __forceinline__ float lrelu(float e) { return (e > 0.f) ? e : NEG_SLOPE * e; }
__device__ __forceinline__ float bperm(int byteaddr, float v) {
  return __uint_as_float((uint)__builtin_amdgcn_ds_bpermute(byteaddr, (int)__float_as_uint(v)));
}

// ---------------- CSR build ----------------
__global__ void zero_int_kernel(int* __restrict__ p, int n) {
  int i = blockIdx.x * blockDim.x + threadIdx.x;
  if (i < n) p[i] = 0;
}

__global__ void hist_kernel(const int* __restrict__ dst, int* __restrict__ deg, int E) {
  int e = blockIdx.x * blockDim.x + threadIdx.x;
  if (e < E) atomicAdd(&deg[dst[e]], 1);
}

__global__ void scan1_kernel(const int* __restrict__ deg, int* __restrict__ part,
                             int* __restrict__ bsums, int n) {
  __shared__ int sdata[256];
  int t = threadIdx.x;
  int base = blockIdx.x * 1024;
  int v[4]; int s = 0;
#pragma unroll
  for (int j = 0; j < 4; ++j) {
    int idx = base + t * 4 + j;
    v[j] = (idx < n) ? deg[idx] : 0;
    s += v[j];
  }
  sdata[t] = s;
  __syncthreads();
  for (int off = 1; off < 256; off <<= 1) {
    int x = 0;
    if (t >= off) x = sdata[t - off];
    __syncthreads();
    if (t >= off) sdata[t] += x;
    __syncthreads();
  }
  if (t == 255) bsums[blockIdx.x] = sdata[255];
  int run = (t > 0) ? sdata[t - 1] : 0;
#pragma unroll
  for (int j = 0; j < 4; ++j) {
    int idx = base + t * 4 + j;
    if (idx < n) part[idx] = run;
    run += v[j];
  }
}

__global__ void scan2_kernel(int* __restrict__ bsums, int nb) {
  __shared__ int sdata[256];
  int t = threadIdx.x;
  sdata[t] = (t < nb) ? bsums[t] : 0;
  __syncthreads();
  for (int off = 1; off < 256; off <<= 1) {
    int x = 0;
    if (t >= off) x = sdata[t - off];
    __syncthreads();
    if (t >= off) sdata[t] += x;
    __syncthreads();
  }
  if (t < nb) bsums[t] = (t > 0) ? sdata[t - 1] : 0;
}

__global__ void scan3_kernel(const int* __restrict__ part, const int* __restrict__ bsums,
                             int* __restrict__ rowptr, int* __restrict__ cursor,
                             int n, int Etot) {
  int i = blockIdx.x * blockDim.x + threadIdx.x;
  if (i < n) {
    int v = part[i] + bsums[i >> 10];
    rowptr[i] = v;
    cursor[i] = v;
  }
  if (i == 0) rowptr[n] = Etot;
}

__global__ void scatter_kernel(const int* __restrict__ src, const int* __restrict__ dst,
                               int* __restrict__ cursor, int* __restrict__ csr_src, int E) {
  int e = blockIdx.x * blockDim.x + threadIdx.x;
  if (e < E) {
    int pos = atomicAdd(&cursor[dst[e]], 1);
    csr_src[pos] = src[e];
  }
}

// ---------------- splits ----------------
__global__ void splitx_kernel(const float* __restrict__ x, ushort* __restrict__ xhi, int n) {
  int base = (blockIdx.x * blockDim.x + threadIdx.x) * 4;
  if (base >= n) return;
  float4 a = *(const float4*)(x + base);
  float v[4] = {a.x, a.y, a.z, a.w};
  ushort hi[4];
#pragma unroll
  for (int j = 0; j < 4; ++j) hi[j] = f2bu(v[j]);
  uint2 ho;
  ho.x = (uint)hi[0] | ((uint)hi[1] << 16);
  ho.y = (uint)hi[2] | ((uint)hi[3] << 16);
  *(uint2*)(xhi + base) = ho;
}

__global__ void splitW_kernel(const float* __restrict__ W, ushort* __restrict__ WtH,
                              ushort* __restrict__ WtL, int K, int Nc) {
  int idx = blockIdx.x * blockDim.x + threadIdx.x;
  if (idx >= K * Nc) return;
  int n = idx / K, k = idx - n * K;
  float w = W[(size_t)k * Nc + n];
  ushort hi = f2bu(w);
  WtH[idx] = hi;
  WtL[idx] = f2bu(w - bu2f(hi));
}

// W3 transposed+split with head-padding: padded col c = h*48+d -> orig col h*47+d (d<47), pad=0.
__global__ void splitW3pad_kernel(const float* __restrict__ W, ushort* __restrict__ WtH,
                                  ushort* __restrict__ WtL, int K) {
  int idx = blockIdx.x * blockDim.x + threadIdx.x;
  if (idx >= K * 192) return;
  int n = idx / K, k = idx - n * K;
  int h = n / 48, d = n - h * 48;
  float w = (d < 47) ? W[(size_t)k * 188 + h * 47 + d] : 0.f;
  ushort hi = f2bu(w);
  WtH[idx] = hi;
  WtL[idx] = f2bu(w - bu2f(hi));
}

// ---------------- split-bf16 MFMA GEMM: A(bf16) x (Bh + Bl) ----------------
#define GBM 128
#define GBN 64
#define GBK 32
#define SA 40

__global__ __launch_bounds__(256) void gemm_split_kernel(
    const ushort* __restrict__ A,
    const ushort* __restrict__ Bh, const ushort* __restrict__ Bl,
    ushort* __restrict__ C, int M, int K, int Nc) {
  __shared__ ushort As[GBM * SA];
  __shared__ ushort BsH[GBN * SA];
  __shared__ ushort BsL[GBN * SA];
  int tid = threadIdx.x;
  int lane = tid & 63;
  int wave = tid >> 6;
  int wm = wave & 1, wn = wave >> 1;
  int rowBase = blockIdx.y * GBM;
  int colBase = blockIdx.x * GBN;
  int q = lane >> 4;
  int ln = lane & 15;

  floatx4 acc[4][2] = {};

  for (int k0 = 0; k0 < K; k0 += GBK) {
#pragma unroll
    for (int it = 0; it < 2; ++it) {
      int i = tid + it * 256;
      int r = i >> 2, seg = i & 3;
      int grow = rowBase + r;
      uint4 vh = {0u, 0u, 0u, 0u};
      if (grow < M) {
        size_t off = (size_t)grow * K + k0 + seg * 8;
        vh = *(const uint4*)(A + off);
      }
      *(uint4*)&As[r * SA + seg * 8] = vh;
    }
    {
      int n = tid >> 2, seg = tid & 3;
      int gcol = colBase + n;
      uint4 vh = {0u, 0u, 0u, 0u}, vl = {0u, 0u, 0u, 0u};
      if (gcol < Nc) {
        size_t off = (size_t)gcol * K + k0 + seg * 8;
        vh = *(const uint4*)(Bh + off);
        vl = *(const uint4*)(Bl + off);
      }
      *(uint4*)&BsH[n * SA + seg * 8] = vh;
      *(uint4*)&BsL[n * SA + seg * 8] = vl;
    }
    __syncthreads();
    short8 af[4], bfH[2], bfL[2];
#pragma unroll
    for (int mt = 0; mt < 4; ++mt) {
      int r = (wm * 64 + mt * 16 + ln) * SA + q * 8;
      af[mt] = *(const short8*)&As[r];
    }
#pragma unroll
    for (int nt = 0; nt < 2; ++nt) {
      int r = (wn * 32 + nt * 16 + ln) * SA + q * 8;
      bfH[nt] = *(const short8*)&BsH[r];
      bfL[nt] = *(const short8*)&BsL[r];
    }
#pragma unroll
    for (int mt = 0; mt < 4; ++mt)
#pragma unroll
      for (int nt = 0; nt < 2; ++nt) {
        acc[mt][nt] = __builtin_amdgcn_mfma_f32_16x16x32_bf16(af[mt], bfH[nt], acc[mt][nt], 0, 0, 0);
        acc[mt][nt] = __builtin_amdgcn_mfma_f32_16x16x32_bf16(af[mt], bfL[nt], acc[mt][nt], 0, 0, 0);
      }
    __syncthreads();
  }
#pragma unroll
  for (int mt = 0; mt < 4; ++mt) {
#pragma unroll
    for (int nt = 0; nt < 2; ++nt) {
      int col = colBase + wn * 32 + nt * 16 + ln;
      if (col < Nc) {
#pragma unroll
        for (int r = 0; r < 4; ++r) {
          int row = rowBase + wm * 64 + mt * 16 + q * 4 + r;
          if (row < M) C[(size_t)row * Nc + col] = f2bu(acc[mt][nt][r]);
        }
      }
    }
  }
}

// ---------------- el/er layer 1/2 (Dh=32, F=128): vectorized uint4 loads ----------------
__global__ void elr128_kernel(const ushort* __restrict__ feat, const float* __restrict__ al,
                              const float* __restrict__ ar, float* __restrict__ el,
                              float* __restrict__ er, int N) {
  int g = blockIdx.x * blockDim.x + threadIdx.x;
  if (g >= N * 4) return;
  int n = g >> 2, h = g & 3;
  const uint4* fp = (const uint4*)(feat + (size_t)n * 128 + h * 32);
  const float* alp = al + h * 32;
  const float* arp = ar + h * 32;
  float sl = 0.f, sr = 0.f;
#pragma unroll
  for (int b = 0; b < 4; ++b) {
    uint4 u = fp[b];
    uint w[4] = {u.x, u.y, u.z, u.w};
#pragma unroll
    for (int j = 0; j < 4; ++j) {
      int d = b * 8 + j * 2;
      float f0 = lo2f(w[j]), f1 = hi2f(w[j]);
      sl += f0 * alp[d] + f1 * alp[d + 1];
      sr += f0 * arp[d] + f1 * arp[d + 1];
    }
  }
  el[g] = sl;
  er[g] = sr;
}

// ---------------- el/er layer 3 (Dh=47, padded row stride 192): scalar ----------------
__global__ void elr3_kernel(const ushort* __restrict__ feat, const float* __restrict__ al,
                            const float* __restrict__ ar, float* __restrict__ el,
                            float* __restrict__ er, int N) {
  int g = blockIdx.x * blockDim.x + threadIdx.x;
  if (g >= N * 4) return;
  int n = g >> 2, h = g & 3;
  const ushort* fp = feat + (size_t)n * 192 + h * 48;
  float sl = 0.f, sr = 0.f;
  for (int d = 0; d < 47; ++d) {
    float f = bu2f(fp[d]);
    sl += f * al[h * 47 + d];
    sr += f * ar[h * 47 + d];
  }
  el[g] = sl;
  er[g] = sr;
}

// ---------------- fused layer 1/2 aggregation, wave/node (round-5 core, hi-only out) ---
__global__ __launch_bounds__(256, 4) void agg128_kernel(
    const int* __restrict__ rowptr, const int* __restrict__ csr_src,
    const ushort* __restrict__ feat, const float* __restrict__ el,
    const float* __restrict__ er, const float* __restrict__ bias,
    ushort* __restrict__ hhi, int N) {
  int lane = threadIdx.x & 63;
  int v = blockIdx.x * 4 + (threadIdx.x >> 6);
  if (v >= N) return;
  float4 er4 = *(const float4*)(er + (size_t)v * 4);
  int r0 = rowptr[v], r1 = rowptr[v + 1];
  int hh = lane & 3;
  float eh = (hh == 0) ? er4.x : (hh == 1) ? er4.y : (hh == 2) ? er4.z : er4.w;
  int hf = lane >> 4;  // head owning features 2*lane, 2*lane+1
  int hf4 = hf * 4;    // bpermute byte base
  const uint* fb = (const uint*)feat;
  floatx2 c01 = {0.f, 0.f};
  float densum = 0.f;
  for (int i0 = r0; i0 < r1; i0 += 16) {
    int i = i0 + (lane >> 2);
    int sv = 0;
    float xv = 0.f;
    if (i < r1) {
      sv = csr_src[i];
      xv = __expf(lrelu(el[(size_t)sv * 4 + hh] + eh));
    }
    // chunk denominator: butterfly sums lanes ≡ (mod 4) = one head's 16 slots
    float ds = xv;
    ds += __shfl_xor(ds, 4);
    ds += __shfl_xor(ds, 8);
    ds += __shfl_xor(ds, 16);
    ds += __shfl_xor(ds, 32);
    densum += ds;
    int cnt = r1 - i0;
    if (cnt > 16) cnt = 16;
    if (cnt == 16) {
#pragma unroll
      for (int j = 0; j < 16; ++j) {
        int s = __builtin_amdgcn_readlane(sv, 4 * j);
        float x = bperm(16 * j + hf4, xv);
        uint u = fb[((size_t)(uint)s << 6) + lane];
        floatx2 f = {lo2f(u), hi2f(u)};
        floatx2 xx = {x, x};
        c01 += xx * f;
      }
    } else {
      for (int j = 0; j < cnt; ++j) {
        int s = __builtin_amdgcn_readlane(sv, 4 * j);
        float x = __shfl(xv, 4 * j + hf);
        uint u = fb[((size_t)(uint)s << 6) + lane];
        floatx2 f = {lo2f(u), hi2f(u)};
        floatx2 xx = {x, x};
        c01 += xx * f;
      }
    }
  }
  float den = __shfl(densum, hf);  // lane hf holds head-hf total
  float o0 = (den > 0.f) ? c01.x / den : 0.f;
  float o1 = (den > 0.f) ? c01.y / den : 0.f;
  o0 = fmaxf(o0 + bias[2 * lane], 0.f);
  o1 = fmaxf(o1 + bias[2 * lane + 1], 0.f);
  ushort h0 = f2bu(o0), h1 = f2bu(o1);
  ((uint*)hhi)[(size_t)v * 64 + lane] = (uint)h0 | ((uint)h1 << 16);
}

// ---------------- fused layer 3 aggregation + bias + head-mean + log_softmax ----------
// Head-aligned padded layout (feat row = 192 = 4 heads x 48): lane l (h=l>>4, k=l&15)
// owns uints h*24+k and h*24+16+(k&7) — all features of ONE head, so a single
// per-edge weight broadcast (agg128's verified pattern). Lanes k>=8 re-read the
// k<8 u1 words (same cache lines) with weight 0 (hoisted mask) — fully convergent.
__global__ __launch_bounds__(256) void agg3_kernel(
    const int* __restrict__ rowptr, const int* __restrict__ csr_src,
    const ushort* __restrict__ feat, const float* __restrict__ el,
    const float* __restrict__ er, const float* __restrict__ bias,
    float* __restrict__ out, int N) {
  __shared__ float svm[4][192];
  int lane = threadIdx.x & 63;
  int w = threadIdx.x >> 6;
  int v = blockIdx.x * 4 + w;
  bool valid = (v < N);
  float4 er4 = {0.f, 0.f, 0.f, 0.f};
  int r0 = 0, r1 = 0;
  if (valid) {
    er4 = *(const float4*)(er + (size_t)v * 4);
    r0 = rowptr[v];
    r1 = rowptr[v + 1];
  }
  int hh = lane & 3;
  float eh = (hh == 0) ? er4.x : (hh == 1) ? er4.y : (hh == 2) ? er4.z : er4.w;
  int h = lane >> 4;   // owned head
  int k = lane & 15;
  bool hasU1 = (k < 8);
  float c1 = hasU1 ? 1.f : 0.f;
  int o0 = h * 24 + k;              // uint index within row (96 uints)
  int o1 = h * 24 + 16 + (k & 7);
  const uint* fpb = (const uint*)feat;  // feat row: 96 uints
  float aa = 0.f, ab = 0.f, ac = 0.f, ad = 0.f;
  float densum = 0.f;
  for (int i0 = r0; i0 < r1; i0 += 16) {
    int i = i0 + (lane >> 2);
    int sv = 0;
    float xv = 0.f;
    if (i < r1) {
      sv = csr_src[i];
      xv = __expf(lrelu(el[(size_t)sv * 4 + hh] + eh));
    }
    // chunk denominator tree (verified r5/r8)
    float ds = xv;
    ds += __shfl_xor(ds, 4);
    ds += __shfl_xor(ds, 8);
    ds += __shfl_xor(ds, 16);
    ds += __shfl_xor(ds, 32);
    densum += ds;
    int cnt = r1 - i0;
    if (cnt > 16) cnt = 16;
#pragma unroll 2
    for (int j = 0; j < cnt; ++j) {
      int s = __builtin_amdgcn_readlane(sv, j * 4);
      float x = __shfl(xv, j * 4 + h);   // single broadcast: lane's head weight
      float x1 = x * c1;
      const uint* fr = fpb + (size_t)(uint)s * 96;
      uint u0 = fr[o0];
      uint u1 = fr[o1];
      aa = fmaf(x, lo2f(u0), aa);
      ab = fmaf(x, hi2f(u0), ab);
      ac = fmaf(x1, lo2f(u1), ac);
      ad = fmaf(x1, hi2f(u1), ad);
    }
  }
  float dh = __shfl(densum, h);          // lane h holds head-h total
  float rd = (dh > 0.f) ? 1.f / dh : 0.f;
  // padded feature indices and original bias indices
  int f0 = h * 48 + 2 * k, f1 = f0 + 1;
  int d2 = 32 + 2 * (k & 7), d3 = d2 + 1;
  int f2 = h * 48 + d2, f3 = h * 48 + d3;
  int b0 = h * 47 + 2 * k, b1 = b0 + 1;
  int b2 = h * 47 + d2;
  int b3i = h * 47 + ((d3 < 47) ? d3 : 46);  // clamp; pad value never read
  float oa = aa * rd + bias[b0];
  float ob = ab * rd + bias[b1];
  if (valid) {
    svm[w][f0] = oa;
    svm[w][f1] = ob;
    if (hasU1) {
      float oc = ac * rd + bias[b2];
      float od = ad * rd + bias[b3i];
      svm[w][f2] = oc;
      svm[w][f3] = od;   // f3 = h*48+47 (pad) when k==7 — never read below
    }
  }
  __syncthreads();
  float val = -1e30f;
  if (valid && lane < 47)
    val = 0.25f * (svm[w][lane] + svm[w][48 + lane] + svm[w][96 + lane] + svm[w][144 + lane]);
  float mx = val;
#pragma unroll
  for (int off = 32; off > 0; off >>= 1) mx = fmaxf(mx, __shfl_xor(mx, off));
  float ex = (lane < 47) ? __expf(val - mx) : 0.f;
  float sum = ex;
#pragma unroll
  for (int off = 32; off > 0; off >>= 1) sum += __shfl_xor(sum, off);
  float res = val - mx - logf(sum);
  if (valid && lane < 47) out[(size_t)v * 47 + lane] = res;
}

// ---------------- host orchestration ----------------
extern "C" void kernel_launch(void* const* d_in, const int* in_sizes, int n_in,
                              void* d_out, int out_size, void* d_ws, size_t ws_size,
                              hipStream_t stream) {
  const int N = 100000, E = 1600000, IN = 256;
  const int F = 128;    // H*D
  const int F3P = 192;  // padded H*C (4 x 48)

  const float* x = (const float*)d_in[0];
  const int* src = (const int*)d_in[1];
  const int* dst = (const int*)d_in[2];
  const float* W1 = (const float*)d_in[3];
  const float* al1 = (const float*)d_in[4];
  const float* ar1 = (const float*)d_in[5];
  const float* b1 = (const float*)d_in[6];
  const float* W2 = (const float*)d_in[7];
  const float* al2 = (const float*)d_in[8];
  const float* ar2 = (const float*)d_in[9];
  const float* b2 = (const float*)d_in[10];
  const float* W3 = (const float*)d_in[11];
  const float* al3 = (const float*)d_in[12];
  const float* ar3 = (const float*)d_in[13];
  const float* b3 = (const float*)d_in[14];

  char* p = (char*)d_ws;
  auto alloc = [&](size_t bytes) -> char* {
    char* r = p;
    p += (bytes + 255) & ~(size_t)255;
    return r;
  };
  ushort* xhi = (ushort*)alloc((size_t)N * IN * sizeof(ushort));
  ushort* feat = (ushort*)alloc((size_t)N * F3P * sizeof(ushort));
  ushort* Wt1h = (ushort*)alloc((size_t)F * IN * sizeof(ushort));
  ushort* Wt1l = (ushort*)alloc((size_t)F * IN * sizeof(ushort));
  ushort* Wt2h = (ushort*)alloc((size_t)F * F * sizeof(ushort));
  ushort* Wt2l = (ushort*)alloc((size_t)F * F * sizeof(ushort));
  ushort* Wt3h = (ushort*)alloc((size_t)F3P * F * sizeof(ushort));
  ushort* Wt3l = (ushort*)alloc((size_t)F3P * F * sizeof(ushort));
  float* el = (float*)alloc((size_t)N * 4 * sizeof(float));
  float* er = (float*)alloc((size_t)N * 4 * sizeof(float));
  int* deg = (int*)alloc((size_t)N * sizeof(int));
  int* part = (int*)alloc((size_t)N * sizeof(int));
  int* bsums = (int*)alloc(256 * sizeof(int));
  int* rowptr = (int*)alloc((size_t)(N + 1) * sizeof(int));
  int* cursor = (int*)alloc((size_t)N * sizeof(int));
  int* csr_src = (int*)alloc((size_t)E * sizeof(int));

  // h (layers 2/3 input) aliases the x split buffer — x is consumed by the
  // layer-1 GEMM before agg128 overwrites it (single-stream ordering).
  ushort* hhi = xhi;

  // ---- CSR build ----
  zero_int_kernel<<<(N + 255) / 256, 256, 0, stream>>>(deg, N);
  hist_kernel<<<(E + 255) / 256, 256, 0, stream>>>(dst, deg, E);
  int nb = (N + 1023) / 1024;
  scan1_kernel<<<nb, 256, 0, stream>>>(deg, part, bsums, N);
  scan2_kernel<<<1, 256, 0, stream>>>(bsums, nb);
  scan3_kernel<<<(N + 255) / 256, 256, 0, stream>>>(part, bsums, rowptr, cursor, N, E);
  scatter_kernel<<<(E + 255) / 256, 256, 0, stream>>>(src, dst, cursor, csr_src, E);

  // ---- splits ----
  splitx_kernel<<<(N * IN / 4 + 255) / 256, 256, 0, stream>>>(x, xhi, N * IN);
  splitW_kernel<<<(IN * F + 255) / 256, 256, 0, stream>>>(W1, Wt1h, Wt1l, IN, F);
  splitW_kernel<<<(F * F + 255) / 256, 256, 0, stream>>>(W2, Wt2h, Wt2l, F, F);
  splitW3pad_kernel<<<(F * F3P + 255) / 256, 256, 0, stream>>>(W3, Wt3h, Wt3l, F);

  int rowBlocks = (N + GBM - 1) / GBM;  // 782
  int nodeBlocks = (N + 3) / 4;

  // ---- layer 1: IN=256 -> 128 ----
  gemm_split_kernel<<<dim3(F / GBN, rowBlocks), 256, 0, stream>>>(
      xhi, Wt1h, Wt1l, feat, N, IN, F);
  elr128_kernel<<<(N * 4 + 255) / 256, 256, 0, stream>>>(feat, al1, ar1, el, er, N);
  agg128_kernel<<<nodeBlocks, 256, 0, stream>>>(rowptr, csr_src, feat, el, er, b1, hhi, N);

  // ---- layer 2: 128 -> 128 ----
  gemm_split_kernel<<<dim3(F / GBN, rowBlocks), 256, 0, stream>>>(
      hhi, Wt2h, Wt2l, feat, N, F, F);
  elr128_kernel<<<(N * 4 + 255) / 256, 256, 0, stream>>>(feat, al2, ar2, el, er, N);
  agg128_kernel<<<nodeBlocks, 256, 0, stream>>>(rowptr, csr_src, feat, el, er, b2, hhi, N);

  // ---- layer 3: 128 -> 192 (padded), fused epilogue ----
  gemm_split_kernel<<<dim3(F3P / GBN, rowBlocks), 256, 0, stream>>>(
      hhi, Wt3h, Wt3l, feat, N, F, F3P);
  elr3_kernel<<<(N * 4 + 255) / 256, 256, 0, stream>>>(feat, al3, ar3, el, er, N);
  agg3_kernel<<<nodeBlocks, 256, 0, stream>>>(rowptr, csr_src, feat, el, er, b3,
                                              (float*)d_out, N);
}

// Round 10
// 829.634 us; speedup vs baseline: 1.2747x; 1.0055x over previous
//
#include <hip/hip_runtime.h>
#include <hip/hip_bf16.h>

typedef unsigned short ushort;
typedef unsigned int uint;
typedef __attribute__((ext_vector_type(8))) short short8;
typedef __attribute__((ext_vector_type(4))) float floatx4;
typedef __attribute__((ext_vector_type(2))) float floatx2;

#define NEG_SLOPE 0.2f

__device__ __forceinline__ float bu2f(ushort u) {
  uint t = ((uint)u) << 16;
  return __uint_as_float(t);
}
__device__ __forceinline__ ushort f2bu(float f) {
  __hip_bfloat16 h = __float2bfloat16(f);
  return *(ushort*)&h;
}
__device__ __forceinline__ float lo2f(uint u) { return __uint_as_float(u << 16); }
__device__ __forceinline__ float hi2f(uint u) { return __uint_as_float(u & 0xffff0000u); }
__device__ __forceinline__ float lrelu(float e) { return (e > 0.f) ? e : NEG_SLOPE * e; }
__device__ __forceinline__ float bperm(int byteaddr, float v) {
  return __uint_as_float((uint)__builtin_amdgcn_ds_bpermute(byteaddr, (int)__float_as_uint(v)));
}

// ---------------- CSR build ----------------
__global__ void zero_int_kernel(int* __restrict__ p, int n) {
  int i = blockIdx.x * blockDim.x + threadIdx.x;
  if (i < n) p[i] = 0;
}

__global__ void hist_kernel(const int* __restrict__ dst, int* __restrict__ deg, int E) {
  int e = blockIdx.x * blockDim.x + threadIdx.x;
  if (e < E) atomicAdd(&deg[dst[e]], 1);
}

__global__ void scan1_kernel(const int* __restrict__ deg, int* __restrict__ part,
                             int* __restrict__ bsums, int n) {
  __shared__ int sdata[256];
  int t = threadIdx.x;
  int base = blockIdx.x * 1024;
  int v[4]; int s = 0;
#pragma unroll
  for (int j = 0; j < 4; ++j) {
    int idx = base + t * 4 + j;
    v[j] = (idx < n) ? deg[idx] : 0;
    s += v[j];
  }
  sdata[t] = s;
  __syncthreads();
  for (int off = 1; off < 256; off <<= 1) {
    int x = 0;
    if (t >= off) x = sdata[t - off];
    __syncthreads();
    if (t >= off) sdata[t] += x;
    __syncthreads();
  }
  if (t == 255) bsums[blockIdx.x] = sdata[255];
  int run = (t > 0) ? sdata[t - 1] : 0;
#pragma unroll
  for (int j = 0; j < 4; ++j) {
    int idx = base + t * 4 + j;
    if (idx < n) part[idx] = run;
    run += v[j];
  }
}

__global__ void scan2_kernel(int* __restrict__ bsums, int nb) {
  __shared__ int sdata[256];
  int t = threadIdx.x;
  sdata[t] = (t < nb) ? bsums[t] : 0;
  __syncthreads();
  for (int off = 1; off < 256; off <<= 1) {
    int x = 0;
    if (t >= off) x = sdata[t - off];
    __syncthreads();
    if (t >= off) sdata[t] += x;
    __syncthreads();
  }
  if (t < nb) bsums[t] = (t > 0) ? sdata[t - 1] : 0;
}

__global__ void scan3_kernel(const int* __restrict__ part, const int* __restrict__ bsums,
                             int* __restrict__ rowptr, int* __restrict__ cursor,
                             int n, int Etot) {
  int i = blockIdx.x * blockDim.x + threadIdx.x;
  if (i < n) {
    int v = part[i] + bsums[i >> 10];
    rowptr[i] = v;
    cursor[i] = v;
  }
  if (i == 0) rowptr[n] = Etot;
}

__global__ void scatter_kernel(const int* __restrict__ src, const int* __restrict__ dst,
                               int* __restrict__ cursor, int* __restrict__ csr_src, int E) {
  int e = blockIdx.x * blockDim.x + threadIdx.x;
  if (e < E) {
    int pos = atomicAdd(&cursor[dst[e]], 1);
    csr_src[pos] = src[e];
  }
}

// ---------------- splits ----------------
__global__ void splitx_kernel(const float* __restrict__ x, ushort* __restrict__ xhi, int n) {
  int base = (blockIdx.x * blockDim.x + threadIdx.x) * 4;
  if (base >= n) return;
  float4 a = *(const float4*)(x + base);
  float v[4] = {a.x, a.y, a.z, a.w};
  ushort hi[4];
#pragma unroll
  for (int j = 0; j < 4; ++j) hi[j] = f2bu(v[j]);
  uint2 ho;
  ho.x = (uint)hi[0] | ((uint)hi[1] << 16);
  ho.y = (uint)hi[2] | ((uint)hi[3] << 16);
  *(uint2*)(xhi + base) = ho;
}

__global__ void splitW_kernel(const float* __restrict__ W, ushort* __restrict__ WtH,
                              ushort* __restrict__ WtL, int K, int Nc) {
  int idx = blockIdx.x * blockDim.x + threadIdx.x;
  if (idx >= K * Nc) return;
  int n = idx / K, k = idx - n * K;
  float w = W[(size_t)k * Nc + n];
  ushort hi = f2bu(w);
  WtH[idx] = hi;
  WtL[idx] = f2bu(w - bu2f(hi));
}

// W3 transposed+split with head-padding: padded col c = h*48+d -> orig col h*47+d (d<47), pad=0.
__global__ void splitW3pad_kernel(const float* __restrict__ W, ushort* __restrict__ WtH,
                                  ushort* __restrict__ WtL, int K) {
  int idx = blockIdx.x * blockDim.x + threadIdx.x;
  if (idx >= K * 192) return;
  int n = idx / K, k = idx - n * K;
  int h = n / 48, d = n - h * 48;
  float w = (d < 47) ? W[(size_t)k * 188 + h * 47 + d] : 0.f;
  ushort hi = f2bu(w);
  WtH[idx] = hi;
  WtL[idx] = f2bu(w - bu2f(hi));
}

// ---------------- split-bf16 MFMA GEMM: A(bf16) x (Bh + Bl) ----------------
#define GBM 128
#define GBN 64
#define GBK 32
#define SA 40

__global__ __launch_bounds__(256) void gemm_split_kernel(
    const ushort* __restrict__ A,
    const ushort* __restrict__ Bh, const ushort* __restrict__ Bl,
    ushort* __restrict__ C, int M, int K, int Nc) {
  __shared__ ushort As[GBM * SA];
  __shared__ ushort BsH[GBN * SA];
  __shared__ ushort BsL[GBN * SA];
  int tid = threadIdx.x;
  int lane = tid & 63;
  int wave = tid >> 6;
  int wm = wave & 1, wn = wave >> 1;
  int rowBase = blockIdx.y * GBM;
  int colBase = blockIdx.x * GBN;
  int q = lane >> 4;
  int ln = lane & 15;

  floatx4 acc[4][2] = {};

  for (int k0 = 0; k0 < K; k0 += GBK) {
#pragma unroll
    for (int it = 0; it < 2; ++it) {
      int i = tid + it * 256;
      int r = i >> 2, seg = i & 3;
      int grow = rowBase + r;
      uint4 vh = {0u, 0u, 0u, 0u};
      if (grow < M) {
        size_t off = (size_t)grow * K + k0 + seg * 8;
        vh = *(const uint4*)(A + off);
      }
      *(uint4*)&As[r * SA + seg * 8] = vh;
    }
    {
      int n = tid >> 2, seg = tid & 3;
      int gcol = colBase + n;
      uint4 vh = {0u, 0u, 0u, 0u}, vl = {0u, 0u, 0u, 0u};
      if (gcol < Nc) {
        size_t off = (size_t)gcol * K + k0 + seg * 8;
        vh = *(const uint4*)(Bh + off);
        vl = *(const uint4*)(Bl + off);
      }
      *(uint4*)&BsH[n * SA + seg * 8] = vh;
      *(uint4*)&BsL[n * SA + seg * 8] = vl;
    }
    __syncthreads();
    short8 af[4], bfH[2], bfL[2];
#pragma unroll
    for (int mt = 0; mt < 4; ++mt) {
      int r = (wm * 64 + mt * 16 + ln) * SA + q * 8;
      af[mt] = *(const short8*)&As[r];
    }
#pragma unroll
    for (int nt = 0; nt < 2; ++nt) {
      int r = (wn * 32 + nt * 16 + ln) * SA + q * 8;
      bfH[nt] = *(const short8*)&BsH[r];
      bfL[nt] = *(const short8*)&BsL[r];
    }
#pragma unroll
    for (int mt = 0; mt < 4; ++mt)
#pragma unroll
      for (int nt = 0; nt < 2; ++nt) {
        acc[mt][nt] = __builtin_amdgcn_mfma_f32_16x16x32_bf16(af[mt], bfH[nt], acc[mt][nt], 0, 0, 0);
        acc[mt][nt] = __builtin_amdgcn_mfma_f32_16x16x32_bf16(af[mt], bfL[nt], acc[mt][nt], 0, 0, 0);
      }
    __syncthreads();
  }
#pragma unroll
  for (int mt = 0; mt < 4; ++mt) {
#pragma unroll
    for (int nt = 0; nt < 2; ++nt) {
      int col = colBase + wn * 32 + nt * 16 + ln;
      if (col < Nc) {
#pragma unroll
        for (int r = 0; r < 4; ++r) {
          int row = rowBase + wm * 64 + mt * 16 + q * 4 + r;
          if (row < M) C[(size_t)row * Nc + col] = f2bu(acc[mt][nt][r]);
        }
      }
    }
  }
}

// ---------------- el/er layer 1/2 (Dh=32, F=128): vectorized uint4 loads ----------------
__global__ void elr128_kernel(const ushort* __restrict__ feat, const float* __restrict__ al,
                              const float* __restrict__ ar, float* __restrict__ el,
                              float* __restrict__ er, int N) {
  int g = blockIdx.x * blockDim.x + threadIdx.x;
  if (g >= N * 4) return;
  int n = g >> 2, h = g & 3;
  const uint4* fp = (const uint4*)(feat + (size_t)n * 128 + h * 32);
  const float* alp = al + h * 32;
  const float* arp = ar + h * 32;
  float sl = 0.f, sr = 0.f;
#pragma unroll
  for (int b = 0; b < 4; ++b) {
    uint4 u = fp[b];
    uint w[4] = {u.x, u.y, u.z, u.w};
#pragma unroll
    for (int j = 0; j < 4; ++j) {
      int d = b * 8 + j * 2;
      float f0 = lo2f(w[j]), f1 = hi2f(w[j]);
      sl += f0 * alp[d] + f1 * alp[d + 1];
      sr += f0 * arp[d] + f1 * arp[d + 1];
    }
  }
  el[g] = sl;
  er[g] = sr;
}

// ---------------- el/er layer 3 (Dh=47, padded row stride 192): vectorized uint4 -------
// Head-row base n*192 + h*48 is 16B-aligned (96B stride). Pad feature (d=47) is exactly
// 0 (GEMM pad weights are 0), so only the alp/arp index needs the compile-time guard.
__global__ void elr3_kernel(const ushort* __restrict__ feat, const float* __restrict__ al,
                            const float* __restrict__ ar, float* __restrict__ el,
                            float* __restrict__ er, int N) {
  int g = blockIdx.x * blockDim.x + threadIdx.x;
  if (g >= N * 4) return;
  int n = g >> 2, h = g & 3;
  const uint4* fp = (const uint4*)(feat + (size_t)n * 192 + h * 48);
  const float* alp = al + h * 47;
  const float* arp = ar + h * 47;
  float sl = 0.f, sr = 0.f;
#pragma unroll
  for (int b = 0; b < 6; ++b) {
    uint4 u = fp[b];
    uint w[4] = {u.x, u.y, u.z, u.w};
#pragma unroll
    for (int j = 0; j < 4; ++j) {
      int d = b * 8 + j * 2;
      float f0 = lo2f(w[j]), f1 = hi2f(w[j]);
      sl += f0 * alp[d];
      sr += f0 * arp[d];
      if (d + 1 < 47) {  // compile-time after unroll; skips only (b=5,j=3) pad slot
        sl += f1 * alp[d + 1];
        sr += f1 * arp[d + 1];
      }
    }
  }
  el[g] = sl;
  er[g] = sr;
}

// ---------------- fused layer 1/2 aggregation, wave/node: uint2-widened gathers --------
// Lane l: c = l&31 (uint2 column = features 4c..4c+3, head hf2=c>>3), e = l>>5 (edge
// parity). Per 2 edges: one uint2 gather (512B/wave-instr), one bpermute, cndmask row
// select. Epilogue pair-sums acc across e via shfl_xor(32); lanes<32 write packed uint2.
// Chunk header (exp + den tree) identical to the r5/r9-verified text.
__global__ __launch_bounds__(256, 4) void agg128_kernel(
    const int* __restrict__ rowptr, const int* __restrict__ csr_src,
    const ushort* __restrict__ feat, const float* __restrict__ el,
    const float* __restrict__ er, const float* __restrict__ bias,
    ushort* __restrict__ hhi, int N) {
  int lane = threadIdx.x & 63;
  int v = blockIdx.x * 4 + (threadIdx.x >> 6);
  if (v >= N) return;
  float4 er4 = *(const float4*)(er + (size_t)v * 4);
  int r0 = rowptr[v], r1 = rowptr[v + 1];
  int hh = lane & 3;
  float eh = (hh == 0) ? er4.x : (hh == 1) ? er4.y : (hh == 2) ? er4.z : er4.w;
  int c = lane & 31;      // uint2 column (features 4c..4c+3)
  int e = lane >> 5;      // edge parity
  int hf2 = c >> 3;       // head owning this lane's features
  int xoffs = 16 * e + 4 * hf2;  // bpermute byte base (reads xv[4*(j+e)+hf2])
  const uint2* fb2 = (const uint2*)feat;  // row = 32 uint2
  float a0 = 0.f, a1 = 0.f, a2 = 0.f, a3 = 0.f;
  float densum = 0.f;
  for (int i0 = r0; i0 < r1; i0 += 16) {
    int i = i0 + (lane >> 2);
    int sv = 0;
    float xv = 0.f;
    if (i < r1) {
      sv = csr_src[i];
      xv = __expf(lrelu(el[(size_t)sv * 4 + hh] + eh));
    }
    // chunk denominator: butterfly sums lanes ≡ (mod 4) = one head's 16 slots
    float ds = xv;
    ds += __shfl_xor(ds, 4);
    ds += __shfl_xor(ds, 8);
    ds += __shfl_xor(ds, 16);
    ds += __shfl_xor(ds, 32);
    densum += ds;
    int cnt = r1 - i0;
    if (cnt > 16) cnt = 16;
    if (cnt == 16) {
#pragma unroll
      for (int j = 0; j < 16; j += 2) {
        int s0 = __builtin_amdgcn_readlane(sv, 4 * j);
        int s1 = __builtin_amdgcn_readlane(sv, 4 * j + 4);
        int srow = e ? s1 : s0;
        float x = bperm(16 * j + xoffs, xv);
        uint2 u = fb2[(size_t)(uint)srow * 32 + c];
        a0 = fmaf(x, lo2f(u.x), a0);
        a1 = fmaf(x, hi2f(u.x), a1);
        a2 = fmaf(x, lo2f(u.y), a2);
        a3 = fmaf(x, hi2f(u.y), a3);
      }
    } else {
      for (int j = 0; j < cnt; j += 2) {
        int s0 = __builtin_amdgcn_readlane(sv, 4 * j);
        int s1 = __builtin_amdgcn_readlane(sv, 4 * j + 4);
        int srow = e ? s1 : s0;
        float x = bperm(16 * j + xoffs, xv);  // masked lanes have xv=0 -> x=0 tail-safe
        uint2 u = fb2[(size_t)(uint)srow * 32 + c];
        a0 = fmaf(x, lo2f(u.x), a0);
        a1 = fmaf(x, hi2f(u.x), a1);
        a2 = fmaf(x, lo2f(u.y), a2);
        a3 = fmaf(x, hi2f(u.y), a3);
      }
    }
  }
  // pair-sum across edge parity (lanes l and l+32 hold the two halves)
  a0 += __shfl_xor(a0, 32);
  a1 += __shfl_xor(a1, 32);
  a2 += __shfl_xor(a2, 32);
  a3 += __shfl_xor(a3, 32);
  float den = __shfl(densum, hf2);  // lane hf2 (<4) holds head total
  if (lane < 32) {
    float rd = (den > 0.f) ? 1.f / den : 0.f;
    float4 b4 = *(const float4*)(bias + 4 * c);
    float o0 = fmaxf(a0 * rd + b4.x, 0.f);
    float o1 = fmaxf(a1 * rd + b4.y, 0.f);
    float o2 = fmaxf(a2 * rd + b4.z, 0.f);
    float o3 = fmaxf(a3 * rd + b4.w, 0.f);
    uint2 pk;
    pk.x = (uint)f2bu(o0) | ((uint)f2bu(o1) << 16);
    pk.y = (uint)f2bu(o2) | ((uint)f2bu(o3) << 16);
    ((uint2*)hhi)[(size_t)v * 32 + c] = pk;
  }
}

// ---------------- fused layer 3 aggregation + bias + head-mean + log_softmax ----------
// (round-9 text, verified)
__global__ __launch_bounds__(256) void agg3_kernel(
    const int* __restrict__ rowptr, const int* __restrict__ csr_src,
    const ushort* __restrict__ feat, const float* __restrict__ el,
    const float* __restrict__ er, const float* __restrict__ bias,
    float* __restrict__ out, int N) {
  __shared__ float svm[4][192];
  int lane = threadIdx.x & 63;
  int w = threadIdx.x >> 6;
  int v = blockIdx.x * 4 + w;
  bool valid = (v < N);
  float4 er4 = {0.f, 0.f, 0.f, 0.f};
  int r0 = 0, r1 = 0;
  if (valid) {
    er4 = *(const float4*)(er + (size_t)v * 4);
    r0 = rowptr[v];
    r1 = rowptr[v + 1];
  }
  int hh = lane & 3;
  float eh = (hh == 0) ? er4.x : (hh == 1) ? er4.y : (hh == 2) ? er4.z : er4.w;
  int h = lane >> 4;   // owned head
  int k = lane & 15;
  bool hasU1 = (k < 8);
  float c1 = hasU1 ? 1.f : 0.f;
  int o0 = h * 24 + k;              // uint index within row (96 uints)
  int o1 = h * 24 + 16 + (k & 7);
  const uint* fpb = (const uint*)feat;  // feat row: 96 uints
  float aa = 0.f, ab = 0.f, ac = 0.f, ad = 0.f;
  float densum = 0.f;
  for (int i0 = r0; i0 < r1; i0 += 16) {
    int i = i0 + (lane >> 2);
    int sv = 0;
    float xv = 0.f;
    if (i < r1) {
      sv = csr_src[i];
      xv = __expf(lrelu(el[(size_t)sv * 4 + hh] + eh));
    }
    float ds = xv;
    ds += __shfl_xor(ds, 4);
    ds += __shfl_xor(ds, 8);
    ds += __shfl_xor(ds, 16);
    ds += __shfl_xor(ds, 32);
    densum += ds;
    int cnt = r1 - i0;
    if (cnt > 16) cnt = 16;
#pragma unroll 2
    for (int j = 0; j < cnt; ++j) {
      int s = __builtin_amdgcn_readlane(sv, j * 4);
      float x = __shfl(xv, j * 4 + h);   // single broadcast: lane's head weight
      float x1 = x * c1;
      const uint* fr = fpb + (size_t)(uint)s * 96;
      uint u0 = fr[o0];
      uint u1 = fr[o1];
      aa = fmaf(x, lo2f(u0), aa);
      ab = fmaf(x, hi2f(u0), ab);
      ac = fmaf(x1, lo2f(u1), ac);
      ad = fmaf(x1, hi2f(u1), ad);
    }
  }
  float dh = __shfl(densum, h);          // lane h holds head-h total
  float rd = (dh > 0.f) ? 1.f / dh : 0.f;
  int f0 = h * 48 + 2 * k, f1 = f0 + 1;
  int d2 = 32 + 2 * (k & 7), d3 = d2 + 1;
  int f2 = h * 48 + d2, f3 = h * 48 + d3;
  int b0 = h * 47 + 2 * k, b1 = b0 + 1;
  int b2 = h * 47 + d2;
  int b3i = h * 47 + ((d3 < 47) ? d3 : 46);  // clamp; pad value never read
  float oa = aa * rd + bias[b0];
  float ob = ab * rd + bias[b1];
  if (valid) {
    svm[w][f0] = oa;
    svm[w][f1] = ob;
    if (hasU1) {
      float oc = ac * rd + bias[b2];
      float od = ad * rd + bias[b3i];
      svm[w][f2] = oc;
      svm[w][f3] = od;   // f3 = h*48+47 (pad) when k==7 — never read below
    }
  }
  __syncthreads();
  float val = -1e30f;
  if (valid && lane < 47)
    val = 0.25f * (svm[w][lane] + svm[w][48 + lane] + svm[w][96 + lane] + svm[w][144 + lane]);
  float mx = val;
#pragma unroll
  for (int off = 32; off > 0; off >>= 1) mx = fmaxf(mx, __shfl_xor(mx, off));
  float ex = (lane < 47) ? __expf(val - mx) : 0.f;
  float sum = ex;
#pragma unroll
  for (int off = 32; off > 0; off >>= 1) sum += __shfl_xor(sum, off);
  float res = val - mx - logf(sum);
  if (valid && lane < 47) out[(size_t)v * 47 + lane] = res;
}

// ---------------- host orchestration ----------------
extern "C" void kernel_launch(void* const* d_in, const int* in_sizes, int n_in,
                              void* d_out, int out_size, void* d_ws, size_t ws_size,
                              hipStream_t stream) {
  const int N = 100000, E = 1600000, IN = 256;
  const int F = 128;    // H*D
  const int F3P = 192;  // padded H*C (4 x 48)

  const float* x = (const float*)d_in[0];
  const int* src = (const int*)d_in[1];
  const int* dst = (const int*)d_in[2];
  const float* W1 = (const float*)d_in[3];
  const float* al1 = (const float*)d_in[4];
  const float* ar1 = (const float*)d_in[5];
  const float* b1 = (const float*)d_in[6];
  const float* W2 = (const float*)d_in[7];
  const float* al2 = (const float*)d_in[8];
  const float* ar2 = (const float*)d_in[9];
  const float* b2 = (const float*)d_in[10];
  const float* W3 = (const float*)d_in[11];
  const float* al3 = (const float*)d_in[12];
  const float* ar3 = (const float*)d_in[13];
  const float* b3 = (const float*)d_in[14];

  char* p = (char*)d_ws;
  auto alloc = [&](size_t bytes) -> char* {
    char* r = p;
    p += (bytes + 255) & ~(size_t)255;
    return r;
  };
  ushort* xhi = (ushort*)alloc((size_t)N * IN * sizeof(ushort));
  ushort* feat = (ushort*)alloc((size_t)N * F3P * sizeof(ushort));
  ushort* Wt1h = (ushort*)alloc((size_t)F * IN * sizeof(ushort));
  ushort* Wt1l = (ushort*)alloc((size_t)F * IN * sizeof(ushort));
  ushort* Wt2h = (ushort*)alloc((size_t)F * F * sizeof(ushort));
  ushort* Wt2l = (ushort*)alloc((size_t)F * F * sizeof(ushort));
  ushort* Wt3h = (ushort*)alloc((size_t)F3P * F * sizeof(ushort));
  ushort* Wt3l = (ushort*)alloc((size_t)F3P * F * sizeof(ushort));
  float* el = (float*)alloc((size_t)N * 4 * sizeof(float));
  float* er = (float*)alloc((size_t)N * 4 * sizeof(float));
  int* deg = (int*)alloc((size_t)N * sizeof(int));
  int* part = (int*)alloc((size_t)N * sizeof(int));
  int* bsums = (int*)alloc(256 * sizeof(int));
  int* rowptr = (int*)alloc((size_t)(N + 1) * sizeof(int));
  int* cursor = (int*)alloc((size_t)N * sizeof(int));
  int* csr_src = (int*)alloc((size_t)E * sizeof(int));

  // h (layers 2/3 input) aliases the x split buffer — x is consumed by the
  // layer-1 GEMM before agg128 overwrites it (single-stream ordering).
  ushort* hhi = xhi;

  // ---- CSR build ----
  zero_int_kernel<<<(N + 255) / 256, 256, 0, stream>>>(deg, N);
  hist_kernel<<<(E + 255) / 256, 256, 0, stream>>>(dst, deg, E);
  int nb = (N + 1023) / 1024;
  scan1_kernel<<<nb, 256, 0, stream>>>(deg, part, bsums, N);
  scan2_kernel<<<1, 256, 0, stream>>>(bsums, nb);
  scan3_kernel<<<(N + 255) / 256, 256, 0, stream>>>(part, bsums, rowptr, cursor, N, E);
  scatter_kernel<<<(E + 255) / 256, 256, 0, stream>>>(src, dst, cursor, csr_src, E);

  // ---- splits ----
  splitx_kernel<<<(N * IN / 4 + 255) / 256, 256, 0, stream>>>(x, xhi, N * IN);
  splitW_kernel<<<(IN * F + 255) / 256, 256, 0, stream>>>(W1, Wt1h, Wt1l, IN, F);
  splitW_kernel<<<(F * F + 255) / 256, 256, 0, stream>>>(W2, Wt2h, Wt2l, F, F);
  splitW3pad_kernel<<<(F * F3P + 255) / 256, 256, 0, stream>>>(W3, Wt3h, Wt3l, F);

  int rowBlocks = (N + GBM - 1) / GBM;  // 782
  int nodeBlocks = (N + 3) / 4;

  // ---- layer 1: IN=256 -> 128 ----
  gemm_split_kernel<<<dim3(F / GBN, rowBlocks), 256, 0, stream>>>(
      xhi, Wt1h, Wt1l, feat, N, IN, F);
  elr128_kernel<<<(N * 4 + 255) / 256, 256, 0, stream>>>(feat, al1, ar1, el, er, N);
  agg128_kernel<<<nodeBlocks, 256, 0, stream>>>(rowptr, csr_src, feat, el, er, b1, hhi, N);

  // ---- layer 2: 128 -> 128 ----
  gemm_split_kernel<<<dim3(F / GBN, rowBlocks), 256, 0, stream>>>(
      hhi, Wt2h, Wt2l, feat, N, F, F);
  elr128_kernel<<<(N * 4 + 255) / 256, 256, 0, stream>>>(feat, al2, ar2, el, er, N);
  agg128_kernel<<<nodeBlocks, 256, 0, stream>>>(rowptr, csr_src, feat, el, er, b2, hhi, N);

  // ---- layer 3: 128 -> 192 (padded), fused epilogue ----
  gemm_split_kernel<<<dim3(F3P / GBN, rowBlocks), 256, 0, stream>>>(
      hhi, Wt3h, Wt3l, feat, N, F, F3P);
  elr3_kernel<<<(N * 4 + 255) / 256, 256, 0, stream>>>(feat, al3, ar3, el, er, N);
  agg3_kernel<<<nodeBlocks, 256, 0, stream>>>(rowptr, csr_src, feat, el, er, b3,
                                              (float*)d_out, N);
}

// Round 11
// 822.099 us; speedup vs baseline: 1.2864x; 1.0092x over previous
//
#include <hip/hip_runtime.h>
#include <hip/hip_bf16.h>

typedef unsigned short ushort;
typedef unsigned int uint;
typedef __attribute__((ext_vector_type(8))) short short8;
typedef __attribute__((ext_vector_type(4))) float floatx4;
typedef __attribute__((ext_vector_type(2))) float floatx2;

#define NEG_SLOPE 0.2f

__device__ __forceinline__ float bu2f(ushort u) {
  uint t = ((uint)u) << 16;
  return __uint_as_float(t);
}
__device__ __forceinline__ ushort f2bu(float f) {
  __hip_bfloat16 h = __float2bfloat16(f);
  return *(ushort*)&h;
}
__device__ __forceinline__ float lo2f(uint u) { return __uint_as_float(u << 16); }
__device__ __forceinline__ float hi2f(uint u) { return __uint_as_float(u & 0xffff0000u); }
__device__ __forceinline__ float lrelu(float e) { return (e > 0.f) ? e : NEG_SLOPE * e; }
__device__ __forceinline__ float bperm(int byteaddr, float v) {
  return __uint_as_float((uint)__builtin_amdgcn_ds_bpermute(byteaddr, (int)__float_as_uint(v)));
}

// ---------------- CSR build ----------------
__global__ void zero_int_kernel(int* __restrict__ p, int n) {
  int i = blockIdx.x * blockDim.x + threadIdx.x;
  if (i < n) p[i] = 0;
}

__global__ void hist_kernel(const int* __restrict__ dst, int* __restrict__ deg, int E) {
  int e = blockIdx.x * blockDim.x + threadIdx.x;
  if (e < E) atomicAdd(&deg[dst[e]], 1);
}

__global__ void scan1_kernel(const int* __restrict__ deg, int* __restrict__ part,
                             int* __restrict__ bsums, int n) {
  __shared__ int sdata[256];
  int t = threadIdx.x;
  int base = blockIdx.x * 1024;
  int v[4]; int s = 0;
#pragma unroll
  for (int j = 0; j < 4; ++j) {
    int idx = base + t * 4 + j;
    v[j] = (idx < n) ? deg[idx] : 0;
    s += v[j];
  }
  sdata[t] = s;
  __syncthreads();
  for (int off = 1; off < 256; off <<= 1) {
    int x = 0;
    if (t >= off) x = sdata[t - off];
    __syncthreads();
    if (t >= off) sdata[t] += x;
    __syncthreads();
  }
  if (t == 255) bsums[blockIdx.x] = sdata[255];
  int run = (t > 0) ? sdata[t - 1] : 0;
#pragma unroll
  for (int j = 0; j < 4; ++j) {
    int idx = base + t * 4 + j;
    if (idx < n) part[idx] = run;
    run += v[j];
  }
}

__global__ void scan2_kernel(int* __restrict__ bsums, int nb) {
  __shared__ int sdata[256];
  int t = threadIdx.x;
  sdata[t] = (t < nb) ? bsums[t] : 0;
  __syncthreads();
  for (int off = 1; off < 256; off <<= 1) {
    int x = 0;
    if (t >= off) x = sdata[t - off];
    __syncthreads();
    if (t >= off) sdata[t] += x;
    __syncthreads();
  }
  if (t < nb) bsums[t] = (t > 0) ? sdata[t - 1] : 0;
}

__global__ void scan3_kernel(const int* __restrict__ part, const int* __restrict__ bsums,
                             int* __restrict__ rowptr, int* __restrict__ cursor,
                             int n, int Etot) {
  int i = blockIdx.x * blockDim.x + threadIdx.x;
  if (i < n) {
    int v = part[i] + bsums[i >> 10];
    rowptr[i] = v;
    cursor[i] = v;
  }
  if (i == 0) rowptr[n] = Etot;
}

__global__ void scatter_kernel(const int* __restrict__ src, const int* __restrict__ dst,
                               int* __restrict__ cursor, int* __restrict__ csr_src, int E) {
  int e = blockIdx.x * blockDim.x + threadIdx.x;
  if (e < E) {
    int pos = atomicAdd(&cursor[dst[e]], 1);
    csr_src[pos] = src[e];
  }
}

// ---------------- splits (hi-only: GEMM is now plain bf16 x bf16) ----------------
__global__ void splitx_kernel(const float* __restrict__ x, ushort* __restrict__ xhi, int n) {
  int base = (blockIdx.x * blockDim.x + threadIdx.x) * 4;
  if (base >= n) return;
  float4 a = *(const float4*)(x + base);
  float v[4] = {a.x, a.y, a.z, a.w};
  ushort hi[4];
#pragma unroll
  for (int j = 0; j < 4; ++j) hi[j] = f2bu(v[j]);
  uint2 ho;
  ho.x = (uint)hi[0] | ((uint)hi[1] << 16);
  ho.y = (uint)hi[2] | ((uint)hi[3] << 16);
  *(uint2*)(xhi + base) = ho;
}

__global__ void splitW_kernel(const float* __restrict__ W, ushort* __restrict__ WtH,
                              int K, int Nc) {
  int idx = blockIdx.x * blockDim.x + threadIdx.x;
  if (idx >= K * Nc) return;
  int n = idx / K, k = idx - n * K;
  WtH[idx] = f2bu(W[(size_t)k * Nc + n]);
}

// W3 transposed with head-padding: padded col c = h*48+d -> orig col h*47+d (d<47), pad=0.
__global__ void splitW3pad_kernel(const float* __restrict__ W, ushort* __restrict__ WtH,
                                  int K) {
  int idx = blockIdx.x * blockDim.x + threadIdx.x;
  if (idx >= K * 192) return;
  int n = idx / K, k = idx - n * K;
  int h = n / 48, d = n - h * 48;
  WtH[idx] = (d < 47) ? f2bu(W[(size_t)k * 188 + h * 47 + d]) : (ushort)0;
}

// ---------------- plain bf16 MFMA GEMM: A x B ----------------
// Precision ladder (r8: dropped Al·Bh, absmax unchanged; r11: drop A·Bl).
// Error budget dominated by bf16 activations + bf16 feat output (each 2^-8 rel);
// bf16 W adds a third comparable term. 1 MFMA/tile, 15.4 KB LDS.
#define GBM 128
#define GBN 64
#define GBK 32
#define SA 40

__global__ __launch_bounds__(256) void gemm_bf16_kernel(
    const ushort* __restrict__ A, const ushort* __restrict__ B,
    ushort* __restrict__ C, int M, int K, int Nc) {
  __shared__ ushort As[GBM * SA];
  __shared__ ushort Bs[GBN * SA];
  int tid = threadIdx.x;
  int lane = tid & 63;
  int wave = tid >> 6;
  int wm = wave & 1, wn = wave >> 1;
  int rowBase = blockIdx.y * GBM;
  int colBase = blockIdx.x * GBN;
  int q = lane >> 4;
  int ln = lane & 15;

  floatx4 acc[4][2] = {};

  for (int k0 = 0; k0 < K; k0 += GBK) {
#pragma unroll
    for (int it = 0; it < 2; ++it) {
      int i = tid + it * 256;
      int r = i >> 2, seg = i & 3;
      int grow = rowBase + r;
      uint4 vh = {0u, 0u, 0u, 0u};
      if (grow < M) {
        size_t off = (size_t)grow * K + k0 + seg * 8;
        vh = *(const uint4*)(A + off);
      }
      *(uint4*)&As[r * SA + seg * 8] = vh;
    }
    {
      int n = tid >> 2, seg = tid & 3;
      int gcol = colBase + n;
      uint4 vh = {0u, 0u, 0u, 0u};
      if (gcol < Nc) {
        size_t off = (size_t)gcol * K + k0 + seg * 8;
        vh = *(const uint4*)(B + off);
      }
      *(uint4*)&Bs[n * SA + seg * 8] = vh;
    }
    __syncthreads();
    short8 af[4], bf[2];
#pragma unroll
    for (int mt = 0; mt < 4; ++mt) {
      int r = (wm * 64 + mt * 16 + ln) * SA + q * 8;
      af[mt] = *(const short8*)&As[r];
    }
#pragma unroll
    for (int nt = 0; nt < 2; ++nt) {
      int r = (wn * 32 + nt * 16 + ln) * SA + q * 8;
      bf[nt] = *(const short8*)&Bs[r];
    }
#pragma unroll
    for (int mt = 0; mt < 4; ++mt)
#pragma unroll
      for (int nt = 0; nt < 2; ++nt)
        acc[mt][nt] = __builtin_amdgcn_mfma_f32_16x16x32_bf16(af[mt], bf[nt], acc[mt][nt], 0, 0, 0);
    __syncthreads();
  }
#pragma unroll
  for (int mt = 0; mt < 4; ++mt) {
#pragma unroll
    for (int nt = 0; nt < 2; ++nt) {
      int col = colBase + wn * 32 + nt * 16 + ln;
      if (col < Nc) {
#pragma unroll
        for (int r = 0; r < 4; ++r) {
          int row = rowBase + wm * 64 + mt * 16 + q * 4 + r;
          if (row < M) C[(size_t)row * Nc + col] = f2bu(acc[mt][nt][r]);
        }
      }
    }
  }
}

// ---------------- el/er layer 1/2 (Dh=32, F=128): vectorized uint4 loads ----------------
__global__ void elr128_kernel(const ushort* __restrict__ feat, const float* __restrict__ al,
                              const float* __restrict__ ar, float* __restrict__ el,
                              float* __restrict__ er, int N) {
  int g = blockIdx.x * blockDim.x + threadIdx.x;
  if (g >= N * 4) return;
  int n = g >> 2, h = g & 3;
  const uint4* fp = (const uint4*)(feat + (size_t)n * 128 + h * 32);
  const float* alp = al + h * 32;
  const float* arp = ar + h * 32;
  float sl = 0.f, sr = 0.f;
#pragma unroll
  for (int b = 0; b < 4; ++b) {
    uint4 u = fp[b];
    uint w[4] = {u.x, u.y, u.z, u.w};
#pragma unroll
    for (int j = 0; j < 4; ++j) {
      int d = b * 8 + j * 2;
      float f0 = lo2f(w[j]), f1 = hi2f(w[j]);
      sl += f0 * alp[d] + f1 * alp[d + 1];
      sr += f0 * arp[d] + f1 * arp[d + 1];
    }
  }
  el[g] = sl;
  er[g] = sr;
}

// ---------------- el/er layer 3 (Dh=47, padded row stride 192): vectorized uint4 -------
__global__ void elr3_kernel(const ushort* __restrict__ feat, const float* __restrict__ al,
                            const float* __restrict__ ar, float* __restrict__ el,
                            float* __restrict__ er, int N) {
  int g = blockIdx.x * blockDim.x + threadIdx.x;
  if (g >= N * 4) return;
  int n = g >> 2, h = g & 3;
  const uint4* fp = (const uint4*)(feat + (size_t)n * 192 + h * 48);
  const float* alp = al + h * 47;
  const float* arp = ar + h * 47;
  float sl = 0.f, sr = 0.f;
#pragma unroll
  for (int b = 0; b < 6; ++b) {
    uint4 u = fp[b];
    uint w[4] = {u.x, u.y, u.z, u.w};
#pragma unroll
    for (int j = 0; j < 4; ++j) {
      int d = b * 8 + j * 2;
      float f0 = lo2f(w[j]), f1 = hi2f(w[j]);
      sl += f0 * alp[d];
      sr += f0 * arp[d];
      if (d + 1 < 47) {  // compile-time after unroll; skips only (b=5,j=3) pad slot
        sl += f1 * alp[d + 1];
        sr += f1 * arp[d + 1];
      }
    }
  }
  el[g] = sl;
  er[g] = sr;
}

// ---------------- fused layer 1/2 aggregation (round-10 text, verified) ----------------
__global__ __launch_bounds__(256, 4) void agg128_kernel(
    const int* __restrict__ rowptr, const int* __restrict__ csr_src,
    const ushort* __restrict__ feat, const float* __restrict__ el,
    const float* __restrict__ er, const float* __restrict__ bias,
    ushort* __restrict__ hhi, int N) {
  int lane = threadIdx.x & 63;
  int v = blockIdx.x * 4 + (threadIdx.x >> 6);
  if (v >= N) return;
  float4 er4 = *(const float4*)(er + (size_t)v * 4);
  int r0 = rowptr[v], r1 = rowptr[v + 1];
  int hh = lane & 3;
  float eh = (hh == 0) ? er4.x : (hh == 1) ? er4.y : (hh == 2) ? er4.z : er4.w;
  int c = lane & 31;      // uint2 column (features 4c..4c+3)
  int e = lane >> 5;      // edge parity
  int hf2 = c >> 3;       // head owning this lane's features
  int xoffs = 16 * e + 4 * hf2;  // bpermute byte base (reads xv[4*(j+e)+hf2])
  const uint2* fb2 = (const uint2*)feat;  // row = 32 uint2
  float a0 = 0.f, a1 = 0.f, a2 = 0.f, a3 = 0.f;
  float densum = 0.f;
  for (int i0 = r0; i0 < r1; i0 += 16) {
    int i = i0 + (lane >> 2);
    int sv = 0;
    float xv = 0.f;
    if (i < r1) {
      sv = csr_src[i];
      xv = __expf(lrelu(el[(size_t)sv * 4 + hh] + eh));
    }
    float ds = xv;
    ds += __shfl_xor(ds, 4);
    ds += __shfl_xor(ds, 8);
    ds += __shfl_xor(ds, 16);
    ds += __shfl_xor(ds, 32);
    densum += ds;
    int cnt = r1 - i0;
    if (cnt > 16) cnt = 16;
    if (cnt == 16) {
#pragma unroll
      for (int j = 0; j < 16; j += 2) {
        int s0 = __builtin_amdgcn_readlane(sv, 4 * j);
        int s1 = __builtin_amdgcn_readlane(sv, 4 * j + 4);
        int srow = e ? s1 : s0;
        float x = bperm(16 * j + xoffs, xv);
        uint2 u = fb2[(size_t)(uint)srow * 32 + c];
        a0 = fmaf(x, lo2f(u.x), a0);
        a1 = fmaf(x, hi2f(u.x), a1);
        a2 = fmaf(x, lo2f(u.y), a2);
        a3 = fmaf(x, hi2f(u.y), a3);
      }
    } else {
      for (int j = 0; j < cnt; j += 2) {
        int s0 = __builtin_amdgcn_readlane(sv, 4 * j);
        int s1 = __builtin_amdgcn_readlane(sv, 4 * j + 4);
        int srow = e ? s1 : s0;
        float x = bperm(16 * j + xoffs, xv);  // masked lanes have xv=0 -> x=0 tail-safe
        uint2 u = fb2[(size_t)(uint)srow * 32 + c];
        a0 = fmaf(x, lo2f(u.x), a0);
        a1 = fmaf(x, hi2f(u.x), a1);
        a2 = fmaf(x, lo2f(u.y), a2);
        a3 = fmaf(x, hi2f(u.y), a3);
      }
    }
  }
  a0 += __shfl_xor(a0, 32);
  a1 += __shfl_xor(a1, 32);
  a2 += __shfl_xor(a2, 32);
  a3 += __shfl_xor(a3, 32);
  float den = __shfl(densum, hf2);  // lane hf2 (<4) holds head total
  if (lane < 32) {
    float rd = (den > 0.f) ? 1.f / den : 0.f;
    float4 b4 = *(const float4*)(bias + 4 * c);
    float o0 = fmaxf(a0 * rd + b4.x, 0.f);
    float o1 = fmaxf(a1 * rd + b4.y, 0.f);
    float o2 = fmaxf(a2 * rd + b4.z, 0.f);
    float o3 = fmaxf(a3 * rd + b4.w, 0.f);
    uint2 pk;
    pk.x = (uint)f2bu(o0) | ((uint)f2bu(o1) << 16);
    pk.y = (uint)f2bu(o2) | ((uint)f2bu(o3) << 16);
    ((uint2*)hhi)[(size_t)v * 32 + c] = pk;
  }
}

// ---------------- fused layer 3 aggregation + bias + head-mean + log_softmax ----------
// Round-9 text + unroll 4 (deeper MLP for the latency-bound gather loop).
__global__ __launch_bounds__(256) void agg3_kernel(
    const int* __restrict__ rowptr, const int* __restrict__ csr_src,
    const ushort* __restrict__ feat, const float* __restrict__ el,
    const float* __restrict__ er, const float* __restrict__ bias,
    float* __restrict__ out, int N) {
  __shared__ float svm[4][192];
  int lane = threadIdx.x & 63;
  int w = threadIdx.x >> 6;
  int v = blockIdx.x * 4 + w;
  bool valid = (v < N);
  float4 er4 = {0.f, 0.f, 0.f, 0.f};
  int r0 = 0, r1 = 0;
  if (valid) {
    er4 = *(const float4*)(er + (size_t)v * 4);
    r0 = rowptr[v];
    r1 = rowptr[v + 1];
  }
  int hh = lane & 3;
  float eh = (hh == 0) ? er4.x : (hh == 1) ? er4.y : (hh == 2) ? er4.z : er4.w;
  int h = lane >> 4;   // owned head
  int k = lane & 15;
  bool hasU1 = (k < 8);
  float c1 = hasU1 ? 1.f : 0.f;
  int o0 = h * 24 + k;              // uint index within row (96 uints)
  int o1 = h * 24 + 16 + (k & 7);
  const uint* fpb = (const uint*)feat;  // feat row: 96 uints
  float aa = 0.f, ab = 0.f, ac = 0.f, ad = 0.f;
  float densum = 0.f;
  for (int i0 = r0; i0 < r1; i0 += 16) {
    int i = i0 + (lane >> 2);
    int sv = 0;
    float xv = 0.f;
    if (i < r1) {
      sv = csr_src[i];
      xv = __expf(lrelu(el[(size_t)sv * 4 + hh] + eh));
    }
    float ds = xv;
    ds += __shfl_xor(ds, 4);
    ds += __shfl_xor(ds, 8);
    ds += __shfl_xor(ds, 16);
    ds += __shfl_xor(ds, 32);
    densum += ds;
    int cnt = r1 - i0;
    if (cnt > 16) cnt = 16;
#pragma unroll 4
    for (int j = 0; j < cnt; ++j) {
      int s = __builtin_amdgcn_readlane(sv, j * 4);
      float x = __shfl(xv, j * 4 + h);   // single broadcast: lane's head weight
      float x1 = x * c1;
      const uint* fr = fpb + (size_t)(uint)s * 96;
      uint u0 = fr[o0];
      uint u1 = fr[o1];
      aa = fmaf(x, lo2f(u0), aa);
      ab = fmaf(x, hi2f(u0), ab);
      ac = fmaf(x1, lo2f(u1), ac);
      ad = fmaf(x1, hi2f(u1), ad);
    }
  }
  float dh = __shfl(densum, h);          // lane h holds head-h total
  float rd = (dh > 0.f) ? 1.f / dh : 0.f;
  int f0 = h * 48 + 2 * k, f1 = f0 + 1;
  int d2 = 32 + 2 * (k & 7), d3 = d2 + 1;
  int f2 = h * 48 + d2, f3 = h * 48 + d3;
  int b0 = h * 47 + 2 * k, b1 = b0 + 1;
  int b2 = h * 47 + d2;
  int b3i = h * 47 + ((d3 < 47) ? d3 : 46);  // clamp; pad value never read
  float oa = aa * rd + bias[b0];
  float ob = ab * rd + bias[b1];
  if (valid) {
    svm[w][f0] = oa;
    svm[w][f1] = ob;
    if (hasU1) {
      float oc = ac * rd + bias[b2];
      float od = ad * rd + bias[b3i];
      svm[w][f2] = oc;
      svm[w][f3] = od;   // f3 = h*48+47 (pad) when k==7 — never read below
    }
  }
  __syncthreads();
  float val = -1e30f;
  if (valid && lane < 47)
    val = 0.25f * (svm[w][lane] + svm[w][48 + lane] + svm[w][96 + lane] + svm[w][144 + lane]);
  float mx = val;
#pragma unroll
  for (int off = 32; off > 0; off >>= 1) mx = fmaxf(mx, __shfl_xor(mx, off));
  float ex = (lane < 47) ? __expf(val - mx) : 0.f;
  float sum = ex;
#pragma unroll
  for (int off = 32; off > 0; off >>= 1) sum += __shfl_xor(sum, off);
  float res = val - mx - logf(sum);
  if (valid && lane < 47) out[(size_t)v * 47 + lane] = res;
}

// ---------------- host orchestration ----------------
extern "C" void kernel_launch(void* const* d_in, const int* in_sizes, int n_in,
                              void* d_out, int out_size, void* d_ws, size_t ws_size,
                              hipStream_t stream) {
  const int N = 100000, E = 1600000, IN = 256;
  const int F = 128;    // H*D
  const int F3P = 192;  // padded H*C (4 x 48)

  const float* x = (const float*)d_in[0];
  const int* src = (const int*)d_in[1];
  const int* dst = (const int*)d_in[2];
  const float* W1 = (const float*)d_in[3];
  const float* al1 = (const float*)d_in[4];
  const float* ar1 = (const float*)d_in[5];
  const float* b1 = (const float*)d_in[6];
  const float* W2 = (const float*)d_in[7];
  const float* al2 = (const float*)d_in[8];
  const float* ar2 = (const float*)d_in[9];
  const float* b2 = (const float*)d_in[10];
  const float* W3 = (const float*)d_in[11];
  const float* al3 = (const float*)d_in[12];
  const float* ar3 = (const float*)d_in[13];
  const float* b3 = (const float*)d_in[14];

  char* p = (char*)d_ws;
  auto alloc = [&](size_t bytes) -> char* {
    char* r = p;
    p += (bytes + 255) & ~(size_t)255;
    return r;
  };
  ushort* xhi = (ushort*)alloc((size_t)N * IN * sizeof(ushort));
  ushort* feat = (ushort*)alloc((size_t)N * F3P * sizeof(ushort));
  ushort* Wt1h = (ushort*)alloc((size_t)F * IN * sizeof(ushort));
  ushort* Wt2h = (ushort*)alloc((size_t)F * F * sizeof(ushort));
  ushort* Wt3h = (ushort*)alloc((size_t)F3P * F * sizeof(ushort));
  float* el = (float*)alloc((size_t)N * 4 * sizeof(float));
  float* er = (float*)alloc((size_t)N * 4 * sizeof(float));
  int* deg = (int*)alloc((size_t)N * sizeof(int));
  int* part = (int*)alloc((size_t)N * sizeof(int));
  int* bsums = (int*)alloc(256 * sizeof(int));
  int* rowptr = (int*)alloc((size_t)(N + 1) * sizeof(int));
  int* cursor = (int*)alloc((size_t)N * sizeof(int));
  int* csr_src = (int*)alloc((size_t)E * sizeof(int));

  // h (layers 2/3 input) aliases the x split buffer — x is consumed by the
  // layer-1 GEMM before agg128 overwrites it (single-stream ordering).
  ushort* hhi = xhi;

  // ---- CSR build ----
  zero_int_kernel<<<(N + 255) / 256, 256, 0, stream>>>(deg, N);
  hist_kernel<<<(E + 255) / 256, 256, 0, stream>>>(dst, deg, E);
  int nb = (N + 1023) / 1024;
  scan1_kernel<<<nb, 256, 0, stream>>>(deg, part, bsums, N);
  scan2_kernel<<<1, 256, 0, stream>>>(bsums, nb);
  scan3_kernel<<<(N + 255) / 256, 256, 0, stream>>>(part, bsums, rowptr, cursor, N, E);
  scatter_kernel<<<(E + 255) / 256, 256, 0, stream>>>(src, dst, cursor, csr_src, E);

  // ---- splits ----
  splitx_kernel<<<(N * IN / 4 + 255) / 256, 256, 0, stream>>>(x, xhi, N * IN);
  splitW_kernel<<<(IN * F + 255) / 256, 256, 0, stream>>>(W1, Wt1h, IN, F);
  splitW_kernel<<<(F * F + 255) / 256, 256, 0, stream>>>(W2, Wt2h, F, F);
  splitW3pad_kernel<<<(F * F3P + 255) / 256, 256, 0, stream>>>(W3, Wt3h, F);

  int rowBlocks = (N + GBM - 1) / GBM;  // 782
  int nodeBlocks = (N + 3) / 4;

  // ---- layer 1: IN=256 -> 128 ----
  gemm_bf16_kernel<<<dim3(F / GBN, rowBlocks), 256, 0, stream>>>(
      xhi, Wt1h, feat, N, IN, F);
  elr128_kernel<<<(N * 4 + 255) / 256, 256, 0, stream>>>(feat, al1, ar1, el, er, N);
  agg128_kernel<<<nodeBlocks, 256, 0, stream>>>(rowptr, csr_src, feat, el, er, b1, hhi, N);

  // ---- layer 2: 128 -> 128 ----
  gemm_bf16_kernel<<<dim3(F / GBN, rowBlocks), 256, 0, stream>>>(
      hhi, Wt2h, feat, N, F, F);
  elr128_kernel<<<(N * 4 + 255) / 256, 256, 0, stream>>>(feat, al2, ar2, el, er, N);
  agg128_kernel<<<nodeBlocks, 256, 0, stream>>>(rowptr, csr_src, feat, el, er, b2, hhi, N);

  // ---- layer 3: 128 -> 192 (padded), fused epilogue ----
  gemm_bf16_kernel<<<dim3(F3P / GBN, rowBlocks), 256, 0, stream>>>(
      hhi, Wt3h, feat, N, F, F3P);
  elr3_kernel<<<(N * 4 + 255) / 256, 256, 0, stream>>>(feat, al3, ar3, el, er, N);
  agg3_kernel<<<nodeBlocks, 256, 0, stream>>>(rowptr, csr_src, feat, el, er, b3,
                                              (float*)d_out, N);
}